// Round 2
// baseline (4898.542 us; speedup 1.0000x reference)
//
#include <hip/hip_runtime.h>
#include <math.h>

typedef unsigned short bf16_t;
using bf16x8 = __attribute__((ext_vector_type(8))) short;
using f32x4  = __attribute__((ext_vector_type(4))) float;

#define DEVFN static __device__ __forceinline__

DEVFN float b2f(bf16_t u){ unsigned v=((unsigned)u)<<16; float f; __builtin_memcpy(&f,&v,4); return f; }
DEVFN bf16_t f2b(float f){ unsigned u; __builtin_memcpy(&u,&f,4); u += 0x7fffu + ((u>>16)&1u); return (bf16_t)(u>>16); }
DEVFN unsigned encf(float f){ unsigned u=__float_as_uint(f); return (u&0x80000000u)? ~u : (u|0x80000000u); }
DEVFN float decf(unsigned e){ return __uint_as_float((e&0x80000000u)? (e^0x80000000u) : ~e); }

constexpr float DN_SCALE = 0.35355339059327373f;   // 64^-0.25
constexpr float RATIO    = 0.06131393394849658f;   // 266^-0.5
constexpr float KEPS     = 1e-4f;

#define GLOAD_LDS16(g, l) __builtin_amdgcn_global_load_lds( \
    (__attribute__((address_space(1))) void*)(g), \
    (__attribute__((address_space(3))) void*)(l), 16, 0, 0)

// ---------------------------------------------------------------- helpers
DEVFN float dot64(const float* __restrict__ a, const float* __restrict__ p){
  float s = 0.f;
  #pragma unroll
  for (int i=0;i<16;i++){
    float4 q = ((const float4*)p)[i];
    s += a[4*i+0]*q.x; s += a[4*i+1]*q.y; s += a[4*i+2]*q.z; s += a[4*i+3]*q.w;
  }
  return s;
}

// ------------------------------------------------ weight transpose + cast
// W [K][N] f32 -> Wt [N][K] bf16.  grid (K/32, N/32), block 256
__global__ __launch_bounds__(256)
void wt_cast(const float* __restrict__ W, bf16_t* __restrict__ Wt, int K, int N)
{
  __shared__ alignas(16) float ts[32][33];
  int t = threadIdx.x;
  int r = t>>3, c4 = (t&7)*4;
  int k0 = blockIdx.x*32, n0 = blockIdx.y*32;
  float4 v = *(const float4*)(W + (size_t)(k0+r)*N + n0 + c4);
  ts[r][c4+0]=v.x; ts[r][c4+1]=v.y; ts[r][c4+2]=v.z; ts[r][c4+3]=v.w;
  __syncthreads();
  ushort4 o;
  o.x = f2b(ts[c4+0][r]); o.y = f2b(ts[c4+1][r]);
  o.z = f2b(ts[c4+2][r]); o.w = f2b(ts[c4+3][r]);
  *(ushort4*)(Wt + (size_t)(n0+r)*K + k0 + c4) = o;
}

__global__ __launch_bounds__(256)
void concat_bias(const float* __restrict__ bq, const float* __restrict__ bk,
                 const float* __restrict__ bv, float* __restrict__ dst)
{
  int t = blockIdx.x*256 + threadIdx.x;   // grid 6 -> 1536
  if (t < 512) dst[t] = bq[t];
  else if (t < 1024) dst[t] = bk[t-512];
  else dst[t] = bv[t-1024];
}

__global__ void mx_init(unsigned* m){ if (threadIdx.x < 32) m[threadIdx.x] = 0u; }

__global__ void zero_out(float* o, long n){
  long i = (long)blockIdx.x*256 + threadIdx.x;
  if (i < n) o[i] = 0.f;
}

// elementwise f32 -> bf16 cast, 4 elems/thread, grid = rows (of 1024)
__global__ __launch_bounds__(256)
void cast_f32_bf16(const float* __restrict__ in, bf16_t* __restrict__ out)
{
  long i = (long)blockIdx.x*256 + threadIdx.x;
  float4 v = ((const float4*)in)[i];
  ushort4 o;
  o.x = f2b(v.x); o.y = f2b(v.y); o.z = f2b(v.z); o.w = f2b(v.w);
  ((ushort4*)out)[i] = o;
}

// ---------------------------------------------------------------- LayerNorm
// one block per row (1024 cols). out = LN(x)*g+b as bf16.
__global__ __launch_bounds__(256)
void ln_kernel(const float* __restrict__ x, const float* __restrict__ g,
               const float* __restrict__ b, bf16_t* __restrict__ out)
{
  long row = blockIdx.x; int t = threadIdx.x;
  float4 v = ((const float4*)x)[row*256 + t];
  float s = v.x+v.y+v.z+v.w;
  #pragma unroll
  for (int o=32;o>0;o>>=1) s += __shfl_xor(s, o);
  __shared__ float r1[4], r2[4];
  if ((t&63)==0) r1[t>>6] = s;
  __syncthreads();
  float mu = (r1[0]+r1[1]+r1[2]+r1[3]) * (1.f/1024.f);
  float dx = v.x-mu, dy = v.y-mu, dz = v.z-mu, dw = v.w-mu;
  float ss = dx*dx+dy*dy+dz*dz+dw*dw;
  #pragma unroll
  for (int o=32;o>0;o>>=1) ss += __shfl_xor(ss, o);
  if ((t&63)==0) r2[t>>6] = ss;
  __syncthreads();
  float var = (r2[0]+r2[1]+r2[2]+r2[3]) * (1.f/1024.f);
  float rs = rsqrtf(var + 1e-5f);
  float4 gg = ((const float4*)g)[t], bb = ((const float4*)b)[t];
  ushort4 o4;
  o4.x = f2b(dx*rs*gg.x+bb.x); o4.y = f2b(dy*rs*gg.y+bb.y);
  o4.z = f2b(dz*rs*gg.z+bb.z); o4.w = f2b(dw*rs*gg.w+bb.w);
  ((ushort4*)out)[row*256+t] = o4;
}

// ---------------------------------------------------------------- GEMM (bf16 MFMA)
// C[M,N] = A[M,K] @ Bt[N,K]^T, 128x128 tile, BK=32, 4 waves, m97 structure.
// Epilogue: +bias, optional +res(f32, may alias Cout), optional exact-GELU,
// optional *gatef(f32, may alias Cout), output f32 or bf16.
template<int RES, int GELU, int GATEF, int OBF>
__global__ __launch_bounds__(256)
void gemm_bt(const bf16_t* __restrict__ A, int lda,
             const bf16_t* __restrict__ Bt, int ldb,
             const float* __restrict__ bias,
             const float* res,
             const float* gatef,
             void* Cout, int N, int K)
{
  __shared__ alignas(16) bf16_t As[128*32];
  __shared__ alignas(16) bf16_t Bs[128*32];
  const int tid = threadIdx.x;
  const int wid = tid>>6, lane = tid&63;
  const int l15 = lane&15, l4 = lane>>4;
  const int wm = wid>>1, wn = wid&1;
  const long m0 = (long)blockIdx.y*128;
  const long n0 = (long)blockIdx.x*128;

  f32x4 acc[4][4];
  #pragma unroll
  for (int i=0;i<4;i++)
    #pragma unroll
    for (int j=0;j<4;j++) acc[i][j] = f32x4{0.f,0.f,0.f,0.f};

  const bf16_t* ga = A  + (size_t)(m0 + (tid>>2))*lda + (tid&3)*8;
  const bf16_t* gb = Bt + (size_t)(n0 + (tid>>2))*ldb + (tid&3)*8;
  bf16_t* lA0 = As + wid*512;
  bf16_t* lA1 = As + 2048 + wid*512;
  bf16_t* lB0 = Bs + wid*512;
  bf16_t* lB1 = Bs + 2048 + wid*512;

  for (int k0 = 0; k0 < K; k0 += 32){
    GLOAD_LDS16(ga,                   lA0);
    GLOAD_LDS16(ga + (size_t)64*lda,  lA1);
    GLOAD_LDS16(gb,                   lB0);
    GLOAD_LDS16(gb + (size_t)64*ldb,  lB1);
    ga += 32; gb += 32;
    __syncthreads();
    bf16x8 af[4], bfr[4];
    #pragma unroll
    for (int i=0;i<4;i++){
      af[i]  = *(const bf16x8*)(As + (wm*64 + i*16 + l15)*32 + l4*8);
      bfr[i] = *(const bf16x8*)(Bs + (wn*64 + i*16 + l15)*32 + l4*8);
    }
    #pragma unroll
    for (int i=0;i<4;i++)
      #pragma unroll
      for (int j=0;j<4;j++)
        acc[i][j] = __builtin_amdgcn_mfma_f32_16x16x32_bf16(af[i], bfr[j], acc[i][j], 0, 0, 0);
    __syncthreads();
  }

  #pragma unroll
  for (int i=0;i<4;i++){
    #pragma unroll
    for (int j=0;j<4;j++){
      #pragma unroll
      for (int r=0;r<4;r++){
        long row = m0 + wm*64 + i*16 + l4*4 + r;
        long col = n0 + wn*64 + j*16 + l15;
        float v = acc[i][j][r] + bias[col];
        if constexpr (RES)   v += res[row*(long)N + col];
        if constexpr (GELU)  v = 0.5f*v*(1.0f + erff(v*0.70710678118654752f));
        if constexpr (GATEF) v *= gatef[row*(long)N + col];
        if constexpr (OBF)  ((bf16_t*)Cout)[row*(long)N + col] = f2b(v);
        else                ((float* )Cout)[row*(long)N + col] = v;
      }
    }
  }
}

// ---------------------------------------------------------------- FAVOR
// qkv layout: [16384][1536] bf16, q at col h*64, k at 512+h*64, v at 1024+h*64.

// F1: per-(b,h) global max of dd_k. grid (16, 32 bh), block 256 (row/thread)
__global__ __launch_bounds__(256)
void favor_kmax(const bf16_t* __restrict__ qkv, const float* __restrict__ pm,
                unsigned* __restrict__ mxk)
{
  int bh = blockIdx.y, b = bh>>3, h = bh&7;
  int t = threadIdx.x;
  int n = blockIdx.x*256 + t;
  long trow = (long)b*4096 + n;
  const bf16_t* kp_ = qkv + trow*1536 + 512 + h*64;
  float kreg[64];
  #pragma unroll
  for (int i=0;i<8;i++){
    uint4 c = ((const uint4*)kp_)[i];
    kreg[i*8+0]=b2f((bf16_t)(c.x&0xffff))*DN_SCALE; kreg[i*8+1]=b2f((bf16_t)(c.x>>16))*DN_SCALE;
    kreg[i*8+2]=b2f((bf16_t)(c.y&0xffff))*DN_SCALE; kreg[i*8+3]=b2f((bf16_t)(c.y>>16))*DN_SCALE;
    kreg[i*8+4]=b2f((bf16_t)(c.z&0xffff))*DN_SCALE; kreg[i*8+5]=b2f((bf16_t)(c.z>>16))*DN_SCALE;
    kreg[i*8+6]=b2f((bf16_t)(c.w&0xffff))*DN_SCALE; kreg[i*8+7]=b2f((bf16_t)(c.w>>16))*DN_SCALE;
  }
  float mx = -1e30f;
  for (int m=0;m<266;m++) mx = fmaxf(mx, dot64(kreg, pm + (size_t)m*64));
  #pragma unroll
  for (int o=32;o>0;o>>=1) mx = fmaxf(mx, __shfl_xor(mx, o));
  __shared__ float red[4];
  if ((t&63)==0) red[t>>6] = mx;
  __syncthreads();
  if (t==0){
    float m2 = fmaxf(fmaxf(red[0],red[1]),fmaxf(red[2],red[3]));
    atomicMax(mxk + bh, encf(m2));
  }
}

// F2a: partial ctx[m][d] and ksum[m] per (bh, chunk of 256 rows); deterministic split.
__global__ __launch_bounds__(256)
void favor_ctx_part(const bf16_t* __restrict__ qkv, const float* __restrict__ pm,
                    const unsigned* __restrict__ mxk,
                    float* __restrict__ Pctx, float* __restrict__ Pks)
{
  int bh = blockIdx.y, b = bh>>3, h = bh&7, chunk = blockIdx.x;
  int t = threadIdx.x;
  __shared__ alignas(16) float kld[8][64];
  __shared__ alignas(16) float vld[8][64];
  __shared__ alignas(16) float kp[8][272];
  __shared__ float diagS[8];
  float acc[68];
  #pragma unroll
  for (int i=0;i<68;i++) acc[i]=0.f;
  float ks0=0.f, ks1=0.f;
  if (t < 48) kp[t/6][266 + t%6] = 0.f;           // zero feature pads once
  float MX = decf(mxk[bh]);
  int g = t>>6, d = t&63;

  for (int st=0; st<32; st++){
    __syncthreads();
    { // stage 8 rows of k (scaled by dn) and v
      int which = t>>7, tt = t&127;
      int r = tt>>4, d0 = (tt&15)*4;
      long trow = (long)b*4096 + chunk*256 + st*8 + r;
      const bf16_t* src = qkv + trow*1536 + (which ? 1024 : 512) + h*64 + d0;
      ushort4 c = *(const ushort4*)src;
      if (which==0){
        kld[r][d0+0]=b2f(c.x)*DN_SCALE; kld[r][d0+1]=b2f(c.y)*DN_SCALE;
        kld[r][d0+2]=b2f(c.z)*DN_SCALE; kld[r][d0+3]=b2f(c.w)*DN_SCALE;
      } else {
        vld[r][d0+0]=b2f(c.x); vld[r][d0+1]=b2f(c.y);
        vld[r][d0+2]=b2f(c.z); vld[r][d0+3]=b2f(c.w);
      }
    }
    __syncthreads();
    if (t < 8){
      float s=0.f;
      #pragma unroll
      for (int i=0;i<64;i++){ float kv=kld[t][i]; s += kv*kv; }
      diagS[t] = 0.5f*s;
    }
    __syncthreads();
    { // kp = ratio*(exp(dd - diag - MX) + eps)
      int r = t&7, mg = t>>3;
      float dg = diagS[r];
      #pragma unroll
      for (int j=0;j<9;j++){
        int m = mg + 32*j;
        if (m < 266){
          float s = dot64(&kld[r][0], pm + (size_t)m*64);
          kp[r][m] = RATIO*(__expf(s - dg - MX) + KEPS);
        }
      }
    }
    __syncthreads();
    { // accumulate ctx partial + ksum partial
      #pragma unroll
      for (int r=0;r<8;r++){
        float vv = vld[r][d];
        const float4* kr = (const float4*)&kp[r][g*68];
        #pragma unroll
        for (int j4=0;j4<17;j4++){
          float4 kk = kr[j4];
          acc[j4*4+0] += kk.x*vv; acc[j4*4+1] += kk.y*vv;
          acc[j4*4+2] += kk.z*vv; acc[j4*4+3] += kk.w*vv;
        }
        ks0 += kp[r][t];
        if (t < 16) ks1 += kp[r][256+t];
      }
    }
  }
  long base = ((long)bh*16 + chunk)*272;
  #pragma unroll
  for (int jj=0;jj<68;jj++)
    Pctx[(base + g*68 + jj)*64 + d] = acc[jj];
  Pks[base + t] = ks0;
  if (t < 16) Pks[base + 256 + t] = ks1;
}

// F2b: reduce partials. grid (68, 32), block 256
__global__ __launch_bounds__(256)
void favor_ctx_reduce(const float* __restrict__ Pctx, const float* __restrict__ Pks,
                      float* __restrict__ ctx, float* __restrict__ ksum)
{
  int bh = blockIdx.y;
  long idx = (long)blockIdx.x*256 + threadIdx.x;   // 0..17407 (= 272*64)
  int m = (int)(idx>>6), d = (int)(idx&63);
  float s = 0.f;
  for (int c=0;c<16;c++) s += Pctx[(((long)bh*16 + c)*272 + m)*64 + d];
  ctx[((long)bh*272 + m)*64 + d] = s;
  if (idx < 272){
    float s2 = 0.f;
    for (int c=0;c<16;c++) s2 += Pks[((long)bh*16 + c)*272 + idx];
    ksum[(long)bh*272 + idx] = s2;
  }
}

// F3: per-row qp (row-max, 2-pass dd), out = (qp@ctx) / (qp.ksum). row/thread.
__global__ __launch_bounds__(256)
void favor_out(const bf16_t* __restrict__ qkv, const float* __restrict__ pm,
               const float* __restrict__ ctx, const float* __restrict__ ksum,
               bf16_t* __restrict__ attn)
{
  int bh = blockIdx.y, b = bh>>3, h = bh&7;
  int n = blockIdx.x*256 + threadIdx.x;
  long trow = (long)b*4096 + n;
  const bf16_t* qp_ = qkv + trow*1536 + h*64;
  float qreg[64];
  #pragma unroll
  for (int i=0;i<8;i++){
    uint4 c = ((const uint4*)qp_)[i];
    qreg[i*8+0]=b2f((bf16_t)(c.x&0xffff))*DN_SCALE; qreg[i*8+1]=b2f((bf16_t)(c.x>>16))*DN_SCALE;
    qreg[i*8+2]=b2f((bf16_t)(c.y&0xffff))*DN_SCALE; qreg[i*8+3]=b2f((bf16_t)(c.y>>16))*DN_SCALE;
    qreg[i*8+4]=b2f((bf16_t)(c.z&0xffff))*DN_SCALE; qreg[i*8+5]=b2f((bf16_t)(c.z>>16))*DN_SCALE;
    qreg[i*8+6]=b2f((bf16_t)(c.w&0xffff))*DN_SCALE; qreg[i*8+7]=b2f((bf16_t)(c.w>>16))*DN_SCALE;
  }
  float dg = 0.f;
  #pragma unroll
  for (int i=0;i<64;i++) dg += qreg[i]*qreg[i];
  dg *= 0.5f;
  float mx = -1e30f;
  for (int m=0;m<266;m++) mx = fmaxf(mx, dot64(qreg, pm + (size_t)m*64));
  float denom = 0.f;
  float acc[64];
  #pragma unroll
  for (int i=0;i<64;i++) acc[i]=0.f;
  const float* ctxb = ctx + (long)bh*272*64;
  const float* ksb  = ksum + (long)bh*272;
  for (int m=0;m<266;m++){
    float s = dot64(qreg, pm + (size_t)m*64);
    float qp = RATIO*(__expf(s - dg - mx) + KEPS);
    denom += qp*ksb[m];
    const float4* cr = (const float4*)(ctxb + (size_t)m*64);
    #pragma unroll
    for (int i=0;i<16;i++){
      float4 c = cr[i];
      acc[4*i+0] += qp*c.x; acc[4*i+1] += qp*c.y;
      acc[4*i+2] += qp*c.z; acc[4*i+3] += qp*c.w;
    }
  }
  float inv = 1.0f/denom;
  bf16_t* dst = attn + trow*512 + h*64;
  #pragma unroll
  for (int i=0;i<16;i++){
    ushort4 o;
    o.x = f2b(acc[4*i+0]*inv); o.y = f2b(acc[4*i+1]*inv);
    o.z = f2b(acc[4*i+2]*inv); o.w = f2b(acc[4*i+3]*inv);
    ((ushort4*)dst)[i] = o;
  }
}

// ---------------------------------------------------------------- launcher
extern "C" void kernel_launch(void* const* d_in, const int* in_sizes, int n_in,
                              void* d_out, int out_size, void* d_ws, size_t ws_size,
                              hipStream_t stream)
{
  (void)in_sizes; (void)n_in; (void)out_size;
  const float* x      = (const float*)d_in[0];
  const float* proj_w = (const float*)d_in[1];
  const float* proj_b = (const float*)d_in[2];
  const float* ln1_g  = (const float*)d_in[3];
  const float* ln1_b  = (const float*)d_in[4];
  const float* wq     = (const float*)d_in[5];
  const float* bq     = (const float*)d_in[6];
  const float* wk     = (const float*)d_in[7];
  const float* bk     = (const float*)d_in[8];
  const float* wv     = (const float*)d_in[9];
  const float* bv     = (const float*)d_in[10];
  const float* wo     = (const float*)d_in[11];
  const float* bo     = (const float*)d_in[12];
  const float* pm     = (const float*)d_in[13];
  const float* ln2_g  = (const float*)d_in[14];
  const float* ln2_b  = (const float*)d_in[15];
  const float* w1     = (const float*)d_in[16];
  const float* b1     = (const float*)d_in[17];
  const float* w2     = (const float*)d_in[18];
  const float* b2     = (const float*)d_in[19];
  float* out = (float*)d_out;
  const size_t MB = 1ull<<20;

  char* ws = (char*)d_ws;
  size_t off = 0;
  auto alloc = [&](size_t bytes)->void*{ void* p = ws + off; off += (bytes + 255) & ~(size_t)255; return p; };
  bf16_t* Wt_proj = (bf16_t*)alloc(2ul*1024*1024);
  bf16_t* Wt_qkv  = (bf16_t*)alloc(2ul*1536*1024);
  bf16_t* Wt_o    = (bf16_t*)alloc(2ul*1024*512);
  bf16_t* Wt_1    = (bf16_t*)alloc(2ul*4096*1024);
  bf16_t* Wt_2    = (bf16_t*)alloc(2ul*1024*4096);
  float*  bqkv    = (float*) alloc(4ul*1536);
  unsigned* mxk   = (unsigned*)alloc(4ul*32);
  float*  ctx     = (float*) alloc(4ul*32*272*64);
  float*  ksum    = (float*) alloc(4ul*32*272);
  char*   R       = (char*)  alloc(0);
  size_t off_R = off;

  // pick FF chunking per available workspace; bail to zero-output if too small
  int NC;
  if      (ws_size >= off_R + 97*MB) NC = 2;
  else if (ws_size >= off_R + 66*MB) NC = 4;
  else { zero_out<<<dim3(65536), 256, 0, stream>>>(out, 16777216L); return; }

  // R-region overlays (phases are stream-serialized; lifetimes are disjoint)
  bf16_t* qkv  = (bf16_t*)(R);            // 48MB, phase A .. favor_out
  bf16_t* h1c  = (bf16_t*)(R + 48*MB);    // 16MB, per-chunk LN1 out (phase A)
  float*  Pks  = (float*) (R + 48*MB);    // 0.6MB (favor)
  bf16_t* attn = (bf16_t*)(R + 49*MB);    // 16MB (favor_out .. wo GEMM)
  long   CH    = 16384/NC;
  bf16_t* h2c  = (bf16_t*)(R);                           // 2CH KB (phase D)
  bf16_t* ff1c = (bf16_t*)(R + 16*MB);                   // CH*8KB
  bf16_t* xbc  = (bf16_t*)(R + 16*MB + (size_t)CH*4096*2); // 2CH KB
  float*  Pctx = (float*)d_out;           // 35.7MB of d_out (dead before wo GEMM)

  // 1) weights -> bf16 transposed
  wt_cast<<<dim3(32,32), 256, 0, stream>>>(proj_w, Wt_proj, 1024, 1024);
  wt_cast<<<dim3(32,16), 256, 0, stream>>>(wq, Wt_qkv,              1024, 512);
  wt_cast<<<dim3(32,16), 256, 0, stream>>>(wk, Wt_qkv + 512*1024,   1024, 512);
  wt_cast<<<dim3(32,16), 256, 0, stream>>>(wv, Wt_qkv + 1024*1024,  1024, 512);
  wt_cast<<<dim3(16,32), 256, 0, stream>>>(wo, Wt_o, 512, 1024);
  wt_cast<<<dim3(32,128),256, 0, stream>>>(w1, Wt_1, 1024, 4096);
  wt_cast<<<dim3(128,32),256, 0, stream>>>(w2, Wt_2, 4096, 1024);
  concat_bias<<<dim3(6), 256, 0, stream>>>(bq, bk, bv, bqkv);

  // 2) phase A: LN1 + qkv GEMM, 2 chunks of 8192 rows
  for (int c = 0; c < 2; c++){
    ln_kernel<<<dim3(8192), 256, 0, stream>>>(x + (size_t)c*8192*1024, ln1_g, ln1_b, h1c);
    gemm_bt<0,0,0,1><<<dim3(12,64), 256, 0, stream>>>(h1c, 1024, Wt_qkv, 1024,
        bqkv, nullptr, nullptr, qkv + (size_t)c*8192*1536, 1536, 1024);
  }

  // 3) FAVOR+ attention (Pctx scratch lives in d_out)
  mx_init<<<dim3(1), 64, 0, stream>>>(mxk);
  favor_kmax<<<dim3(16,32), 256, 0, stream>>>(qkv, pm, mxk);
  favor_ctx_part<<<dim3(16,32), 256, 0, stream>>>(qkv, pm, mxk, Pctx, Pks);
  favor_ctx_reduce<<<dim3(68,32), 256, 0, stream>>>(Pctx, Pks, ctx, ksum);
  favor_out<<<dim3(16,32), 256, 0, stream>>>(qkv, pm, ctx, ksum, attn);

  // 4) x2 = x + attn @ wo + bo  -> d_out (f32), fully overwrites Pctx scratch
  gemm_bt<1,0,0,0><<<dim3(8,128), 256, 0, stream>>>(attn, 512, Wt_o, 512,
      bo, x, nullptr, out, 1024, 512);

  // 5) phase D per chunk: LN2 -> ff1(gelu) -> ff2(+res, in-place) -> gate(in-place)
  for (int c = 0; c < NC; c++){
    float* xrow = out + (size_t)c*CH*1024;
    ln_kernel<<<dim3((unsigned)CH), 256, 0, stream>>>(xrow, ln2_g, ln2_b, h2c);
    gemm_bt<0,1,0,1><<<dim3(32,(unsigned)(CH/128)), 256, 0, stream>>>(h2c, 1024, Wt_1, 1024,
        b1, nullptr, nullptr, ff1c, 4096, 1024);
    gemm_bt<1,0,0,0><<<dim3(8,(unsigned)(CH/128)), 256, 0, stream>>>(ff1c, 4096, Wt_2, 4096,
        b2, xrow, nullptr, xrow, 1024, 4096);
    cast_f32_bf16<<<dim3((unsigned)CH), 256, 0, stream>>>(x + (size_t)c*CH*1024, xbc);
    gemm_bt<0,0,1,0><<<dim3(8,(unsigned)(CH/128)), 256, 0, stream>>>(xbc, 1024, Wt_proj, 1024,
        proj_b, nullptr, xrow, xrow, 1024, 1024);
  }
}

// Round 3
// 1203.822 us; speedup vs baseline: 4.0692x; 4.0692x over previous
//
#include <hip/hip_runtime.h>
#include <math.h>

typedef unsigned short bf16_t;
using bf16x8 = __attribute__((ext_vector_type(8))) short;
using f32x4  = __attribute__((ext_vector_type(4))) float;

#define DEVFN static __device__ __forceinline__

DEVFN float b2f(bf16_t u){ unsigned v=((unsigned)u)<<16; float f; __builtin_memcpy(&f,&v,4); return f; }
DEVFN bf16_t f2b(float f){ unsigned u; __builtin_memcpy(&u,&f,4); u += 0x7fffu + ((u>>16)&1u); return (bf16_t)(u>>16); }
DEVFN unsigned encf(float f){ unsigned u=__float_as_uint(f); return (u&0x80000000u)? ~u : (u|0x80000000u); }
DEVFN float decf(unsigned e){ return __uint_as_float((e&0x80000000u)? (e^0x80000000u) : ~e); }

constexpr float DN_SCALE = 0.35355339059327373f;   // 64^-0.25
constexpr float RATIO    = 0.06131393394849658f;   // 266^-0.5
constexpr float KEPS     = 1e-4f;
#define MPAD 288   // 266 features padded to 9*32

#define GLOAD_LDS16(g, l) __builtin_amdgcn_global_load_lds( \
    (__attribute__((address_space(1))) void*)(g), \
    (__attribute__((address_space(3))) void*)(l), 16, 0, 0)

#define MFMA16(a,b,c) __builtin_amdgcn_mfma_f32_16x16x32_bf16(a,b,c,0,0,0)

// ------------------------------------------------ weight transpose + cast
__global__ __launch_bounds__(256)
void wt_cast(const float* __restrict__ W, bf16_t* __restrict__ Wt, int K, int N)
{
  __shared__ alignas(16) float ts[32][33];
  int t = threadIdx.x;
  int r = t>>3, c4 = (t&7)*4;
  int k0 = blockIdx.x*32, n0 = blockIdx.y*32;
  float4 v = *(const float4*)(W + (size_t)(k0+r)*N + n0 + c4);
  ts[r][c4+0]=v.x; ts[r][c4+1]=v.y; ts[r][c4+2]=v.z; ts[r][c4+3]=v.w;
  __syncthreads();
  ushort4 o;
  o.x = f2b(ts[c4+0][r]); o.y = f2b(ts[c4+1][r]);
  o.z = f2b(ts[c4+2][r]); o.w = f2b(ts[c4+3][r]);
  *(ushort4*)(Wt + (size_t)(n0+r)*K + k0 + c4) = o;
}

__global__ __launch_bounds__(256)
void concat_bias(const float* __restrict__ bq, const float* __restrict__ bk,
                 const float* __restrict__ bv, float* __restrict__ dst)
{
  int t = blockIdx.x*256 + threadIdx.x;
  if (t < 512) dst[t] = bq[t];
  else if (t < 1024) dst[t] = bk[t-512];
  else dst[t] = bv[t-1024];
}

__global__ void mx_init(unsigned* m){ if (threadIdx.x < 32) m[threadIdx.x] = 0u; }

__global__ void zero_out(float* o, long n){
  long i = (long)blockIdx.x*256 + threadIdx.x;
  if (i < n) o[i] = 0.f;
}

// pmb[m][64] bf16 = pm * dn, zero-padded rows 266..287
__global__ __launch_bounds__(256)
void pm_cast(const float* __restrict__ pm, bf16_t* __restrict__ pmb)
{
  int idx = blockIdx.x*256 + threadIdx.x;      // grid 72 -> 18432
  int r = idx>>6, c = idx&63;
  pmb[idx] = (r < 266) ? f2b(pm[r*64+c]*DN_SCALE) : (bf16_t)0;
}

// diag for q and k: 0.5*dn^2 * sum(d^2). grid (16, 32bh)
__global__ __launch_bounds__(256)
void diag_kernel(const bf16_t* __restrict__ qkv, float* __restrict__ diagq,
                 float* __restrict__ diagk)
{
  int bh = blockIdx.y, b = bh>>3, h = bh&7;
  int n = blockIdx.x*256 + threadIdx.x;
  long trow = (long)b*4096 + n;
  const bf16_t* qp_ = qkv + trow*1536 + h*64;
  const bf16_t* kp_ = qkv + trow*1536 + 512 + h*64;
  float sq = 0.f, sk = 0.f;
  #pragma unroll
  for (int i=0;i<8;i++){
    uint4 cq = ((const uint4*)qp_)[i];
    uint4 ck = ((const uint4*)kp_)[i];
    unsigned w[4] = {cq.x,cq.y,cq.z,cq.w};
    unsigned v[4] = {ck.x,ck.y,ck.z,ck.w};
    #pragma unroll
    for (int j=0;j<4;j++){
      float a0=b2f((bf16_t)(w[j]&0xffff)), a1=b2f((bf16_t)(w[j]>>16));
      float b0=b2f((bf16_t)(v[j]&0xffff)), b1=b2f((bf16_t)(v[j]>>16));
      sq += a0*a0 + a1*a1; sk += b0*b0 + b1*b1;
    }
  }
  float sc = 0.5f*DN_SCALE*DN_SCALE;
  diagq[(long)bh*4096 + n] = sq*sc;
  diagk[(long)bh*4096 + n] = sk*sc;
}

// v transpose: qkv v-part -> vT[bh*64+d][4096]. grid (128, 64), block 256
__global__ __launch_bounds__(256)
void vt_trans(const bf16_t* __restrict__ qkv, bf16_t* __restrict__ vT)
{
  __shared__ ushort ts[32][36];
  int by = blockIdx.y;
  int bh = by>>1, dt = by&1, b = bh>>3, h = bh&7;
  int n0 = blockIdx.x*32;
  int t = threadIdx.x, r = t>>3, c4 = (t&7)*4;
  ushort4 v = *(const ushort4*)(qkv + ((size_t)b*4096 + n0 + r)*1536 + 1024 + h*64 + dt*32 + c4);
  ts[r][c4+0]=v.x; ts[r][c4+1]=v.y; ts[r][c4+2]=v.z; ts[r][c4+3]=v.w;
  __syncthreads();
  ushort4 o;
  o.x = ts[c4+0][r]; o.y = ts[c4+1][r]; o.z = ts[c4+2][r]; o.w = ts[c4+3][r];
  *(ushort4*)(vT + ((size_t)bh*64 + dt*32 + r)*4096 + n0 + c4) = o;
}

// ---------------------------------------------------------------- LayerNorm
__global__ __launch_bounds__(256)
void ln_kernel(const float* __restrict__ x, const float* __restrict__ g,
               const float* __restrict__ b, bf16_t* __restrict__ out)
{
  long row = blockIdx.x; int t = threadIdx.x;
  float4 v = ((const float4*)x)[row*256 + t];
  float s = v.x+v.y+v.z+v.w;
  #pragma unroll
  for (int o=32;o>0;o>>=1) s += __shfl_xor(s, o);
  __shared__ float r1[4], r2[4];
  if ((t&63)==0) r1[t>>6] = s;
  __syncthreads();
  float mu = (r1[0]+r1[1]+r1[2]+r1[3]) * (1.f/1024.f);
  float dx = v.x-mu, dy = v.y-mu, dz = v.z-mu, dw = v.w-mu;
  float ss = dx*dx+dy*dy+dz*dz+dw*dw;
  #pragma unroll
  for (int o=32;o>0;o>>=1) ss += __shfl_xor(ss, o);
  if ((t&63)==0) r2[t>>6] = ss;
  __syncthreads();
  float var = (r2[0]+r2[1]+r2[2]+r2[3]) * (1.f/1024.f);
  float rs = rsqrtf(var + 1e-5f);
  float4 gg = ((const float4*)g)[t], bb = ((const float4*)b)[t];
  ushort4 o4;
  o4.x = f2b(dx*rs*gg.x+bb.x); o4.y = f2b(dy*rs*gg.y+bb.y);
  o4.z = f2b(dz*rs*gg.z+bb.z); o4.w = f2b(dw*rs*gg.w+bb.w);
  ((ushort4*)out)[row*256+t] = o4;
}

// f32 -> bf16 cast, grid = rows (of 1024)
__global__ __launch_bounds__(256)
void cast_f32_bf16(const float* __restrict__ in, bf16_t* __restrict__ out)
{
  long i = (long)blockIdx.x*256 + threadIdx.x;
  float4 v = ((const float4*)in)[i];
  ushort4 o;
  o.x = f2b(v.x); o.y = f2b(v.y); o.z = f2b(v.z); o.w = f2b(v.w);
  ((ushort4*)out)[i] = o;
}

// ---------------------------------------------------------------- GEMM (bf16 MFMA)
template<int RES, int GELU, int GATEF, int OBF>
__global__ __launch_bounds__(256)
void gemm_bt(const bf16_t* __restrict__ A, int lda,
             const bf16_t* __restrict__ Bt, int ldb,
             const float* __restrict__ bias,
             const float* res,
             const float* gatef,
             void* Cout, int N, int K)
{
  __shared__ alignas(16) bf16_t As[128*32];
  __shared__ alignas(16) bf16_t Bs[128*32];
  const int tid = threadIdx.x;
  const int wid = tid>>6, lane = tid&63;
  const int l15 = lane&15, l4 = lane>>4;
  const int wm = wid>>1, wn = wid&1;
  const long m0 = (long)blockIdx.y*128;
  const long n0 = (long)blockIdx.x*128;

  f32x4 acc[4][4];
  #pragma unroll
  for (int i=0;i<4;i++)
    #pragma unroll
    for (int j=0;j<4;j++) acc[i][j] = f32x4{0.f,0.f,0.f,0.f};

  const bf16_t* ga = A  + (size_t)(m0 + (tid>>2))*lda + (tid&3)*8;
  const bf16_t* gb = Bt + (size_t)(n0 + (tid>>2))*ldb + (tid&3)*8;
  bf16_t* lA0 = As + wid*512;
  bf16_t* lA1 = As + 2048 + wid*512;
  bf16_t* lB0 = Bs + wid*512;
  bf16_t* lB1 = Bs + 2048 + wid*512;

  for (int k0 = 0; k0 < K; k0 += 32){
    GLOAD_LDS16(ga,                   lA0);
    GLOAD_LDS16(ga + (size_t)64*lda,  lA1);
    GLOAD_LDS16(gb,                   lB0);
    GLOAD_LDS16(gb + (size_t)64*ldb,  lB1);
    ga += 32; gb += 32;
    __syncthreads();
    bf16x8 af[4], bfr[4];
    #pragma unroll
    for (int i=0;i<4;i++){
      af[i]  = *(const bf16x8*)(As + (wm*64 + i*16 + l15)*32 + l4*8);
      bfr[i] = *(const bf16x8*)(Bs + (wn*64 + i*16 + l15)*32 + l4*8);
    }
    #pragma unroll
    for (int i=0;i<4;i++)
      #pragma unroll
      for (int j=0;j<4;j++)
        acc[i][j] = MFMA16(af[i], bfr[j], acc[i][j]);
    __syncthreads();
  }

  #pragma unroll
  for (int i=0;i<4;i++){
    #pragma unroll
    for (int j=0;j<4;j++){
      #pragma unroll
      for (int r=0;r<4;r++){
        long row = m0 + wm*64 + i*16 + l4*4 + r;
        long col = n0 + wn*64 + j*16 + l15;
        float v = acc[i][j][r] + bias[col];
        if constexpr (RES)   v += res[row*(long)N + col];
        if constexpr (GELU)  v = 0.5f*v*(1.0f + erff(v*0.70710678118654752f));
        if constexpr (GATEF) v *= gatef[row*(long)N + col];
        if constexpr (OBF)  ((bf16_t*)Cout)[row*(long)N + col] = f2b(v);
        else                ((float* )Cout)[row*(long)N + col] = v;
      }
    }
  }
}

// ---------------------------------------------------------------- FAVOR (MFMA)
// qkv: [16384][1536] bf16, q @ h*64, k @ 512+h*64, v @ 1024+h*64.

// dd-max over all (n,m) per bh. grid (64, 32), block 256 (4 waves x 16 rows)
__global__ __launch_bounds__(256,2)
void favor_kmax2(const bf16_t* __restrict__ qkv, const bf16_t* __restrict__ pmb,
                 unsigned* __restrict__ mxk)
{
  int bh = blockIdx.y, b = bh>>3, h = bh&7;
  int t = threadIdx.x, wid = t>>6, lane = t&63;
  int l15 = lane&15, l4 = lane>>4;
  int n0 = blockIdx.x*64, row0 = wid*16;
  f32x4 acc[18];
  #pragma unroll
  for (int c=0;c<18;c++) acc[c] = f32x4{0.f,0.f,0.f,0.f};
  const bf16_t* abase = qkv + ((size_t)(b*4096) + n0 + row0 + l15)*1536 + 512 + h*64;
  #pragma unroll
  for (int kh=0;kh<2;kh++){
    bf16x8 a = *(const bf16x8*)(abase + kh*32 + l4*8);
    #pragma unroll
    for (int ct=0;ct<18;ct++){
      bf16x8 bb = *(const bf16x8*)(pmb + (ct*16+l15)*64 + kh*32 + l4*8);
      acc[ct] = MFMA16(a, bb, acc[ct]);
    }
  }
  float mx = -3e38f;
  #pragma unroll
  for (int ct=0;ct<18;ct++){
    if (ct*16 + l15 < 266){
      #pragma unroll
      for (int r=0;r<4;r++) mx = fmaxf(mx, acc[ct][r]);
    }
  }
  #pragma unroll
  for (int o=32;o>0;o>>=1) mx = fmaxf(mx, __shfl_xor(mx, o));
  __shared__ float red[4];
  if (lane==0) red[wid] = mx;
  __syncthreads();
  if (t==0){
    float m2 = fmaxf(fmaxf(red[0],red[1]),fmaxf(red[2],red[3]));
    atomicMax(mxk + bh, encf(m2));
  }
}

// kp = ratio*(exp(dd - diag - MX)+eps) -> kp[bhl][n][MPAD]. grid (64, KG)
__global__ __launch_bounds__(256,2)
void favor_kp(const bf16_t* __restrict__ qkv, const bf16_t* __restrict__ pmb,
              const unsigned* __restrict__ mxk, const float* __restrict__ diagk,
              bf16_t* __restrict__ kp, int bh0)
{
  int bhl = blockIdx.y, bh = bh0 + bhl, b = bh>>3, h = bh&7;
  int t = threadIdx.x, wid = t>>6, lane = t&63;
  int l15 = lane&15, l4 = lane>>4;
  int n0 = blockIdx.x*64, row0 = wid*16;
  f32x4 acc[18];
  #pragma unroll
  for (int c=0;c<18;c++) acc[c] = f32x4{0.f,0.f,0.f,0.f};
  const bf16_t* abase = qkv + ((size_t)(b*4096) + n0 + row0 + l15)*1536 + 512 + h*64;
  #pragma unroll
  for (int kh=0;kh<2;kh++){
    bf16x8 a = *(const bf16x8*)(abase + kh*32 + l4*8);
    #pragma unroll
    for (int ct=0;ct<18;ct++){
      bf16x8 bb = *(const bf16x8*)(pmb + (ct*16+l15)*64 + kh*32 + l4*8);
      acc[ct] = MFMA16(a, bb, acc[ct]);
    }
  }
  float MX = decf(mxk[bh]);
  float dg[4];
  #pragma unroll
  for (int r=0;r<4;r++) dg[r] = diagk[(size_t)bh*4096 + n0 + row0 + l4*4 + r];
  #pragma unroll
  for (int ct=0;ct<18;ct++){
    int col = ct*16 + l15;
    #pragma unroll
    for (int r=0;r<4;r++){
      float v = (col < 266) ? RATIO*(__expf(acc[ct][r] - dg[r] - MX) + KEPS) : 0.f;
      kp[((size_t)bhl*4096 + n0 + row0 + l4*4 + r)*MPAD + col] = f2b(v);
    }
  }
}

// kp [bhl][4096][MPAD] -> kpT [bhl][MPAD][4096]. grid (128, 9, KG)
__global__ __launch_bounds__(256)
void trans_kp(const bf16_t* __restrict__ kp, bf16_t* __restrict__ kpT)
{
  __shared__ ushort ts[32][36];
  int bhl = blockIdx.z;
  int n0 = blockIdx.x*32, m0 = blockIdx.y*32;
  int t = threadIdx.x, r = t>>3, c4 = (t&7)*4;
  ushort4 v = *(const ushort4*)(kp + ((size_t)bhl*4096 + n0 + r)*MPAD + m0 + c4);
  ts[r][c4+0]=v.x; ts[r][c4+1]=v.y; ts[r][c4+2]=v.z; ts[r][c4+3]=v.w;
  __syncthreads();
  ushort4 o;
  o.x = ts[c4+0][r]; o.y = ts[c4+1][r]; o.z = ts[c4+2][r]; o.w = ts[c4+3][r];
  *(ushort4*)(kpT + ((size_t)bhl*MPAD + m0 + r)*4096 + n0 + c4) = o;
}

// ksum[m] = sum_n kp. one wave per m-row. grid (KG*68)
__global__ __launch_bounds__(256)
void ksum_kernel(const bf16_t* __restrict__ kpT, float* __restrict__ ksumf, int bh0)
{
  int t = threadIdx.x, wid = t>>6, lane = t&63;
  int rr = blockIdx.x*4 + wid;
  int bhl = rr/272, m = rr%272;
  const bf16_t* row = kpT + ((size_t)bhl*MPAD + m)*4096;
  float s = 0.f;
  #pragma unroll
  for (int j=0;j<8;j++){
    bf16x8 v = *(const bf16x8*)(row + j*512 + lane*8);
    #pragma unroll
    for (int e=0;e<8;e++) s += b2f((bf16_t)v[e]);
  }
  #pragma unroll
  for (int o=32;o>0;o>>=1) s += __shfl_xor(s, o);
  if (lane==0) ksumf[(size_t)(bh0+bhl)*MPAD + m] = s;
}

// ctx GEMM: ctxT[bh][d][m] = sum_n kpT[m][n]*vT[d][n]. grid (17, KG)
__global__ __launch_bounds__(256,2)
void ctx_gemm(const bf16_t* __restrict__ kpT, const bf16_t* __restrict__ vT,
              bf16_t* __restrict__ ctxT, int bh0)
{
  int bhl = blockIdx.y, bh = bh0 + bhl;
  int t = threadIdx.x, wid = t>>6, lane = t&63;
  int l15 = lane&15, l4 = lane>>4;
  int m0 = blockIdx.x*16;
  f32x4 acc[4];
  #pragma unroll
  for (int c=0;c<4;c++) acc[c] = f32x4{0.f,0.f,0.f,0.f};
  const bf16_t* Abase = kpT + ((size_t)bhl*MPAD + m0 + l15)*4096;
  const bf16_t* Bbase = vT + ((size_t)bh*64)*4096;
  for (int k = wid*1024; k < wid*1024 + 1024; k += 32){
    bf16x8 a = *(const bf16x8*)(Abase + k + l4*8);
    #pragma unroll
    for (int ct=0;ct<4;ct++){
      bf16x8 bb = *(const bf16x8*)(Bbase + (size_t)(ct*16+l15)*4096 + k + l4*8);
      acc[ct] = MFMA16(a, bb, acc[ct]);
    }
  }
  __shared__ float red[4][4][16][16];
  #pragma unroll
  for (int ct=0;ct<4;ct++)
    #pragma unroll
    for (int r=0;r<4;r++) red[wid][ct][l4*4+r][l15] = acc[ct][r];
  __syncthreads();
  #pragma unroll
  for (int i=0;i<4;i++){
    int e = i*256 + t;
    int ct = e>>8, row = (e>>4)&15, col = e&15;
    float s = ((red[0][ct][row][col] + red[1][ct][row][col])
             + (red[2][ct][row][col] + red[3][ct][row][col]));
    ctxT[((size_t)bh*64 + ct*16 + col)*MPAD + m0 + row] = f2b(s);
  }
}

// fused q-side: dd MFMA -> rowmax -> qp -> LDS -> out MFMA * dinv -> attn
// grid (64, 32), block 256 (4 waves x 16 rows)
__global__ __launch_bounds__(256,2)
void favor_q(const bf16_t* __restrict__ qkv, const bf16_t* __restrict__ pmb,
             const float* __restrict__ diagq, const float* __restrict__ ksumf,
             const bf16_t* __restrict__ ctxT, bf16_t* __restrict__ attn)
{
  __shared__ alignas(16) ushort qpLds[64*296];
  __shared__ float ksLds[288];
  int bh = blockIdx.y, b = bh>>3, h = bh&7;
  int t = threadIdx.x, wid = t>>6, lane = t&63;
  int l15 = lane&15, l4 = lane>>4;
  int n0 = blockIdx.x*64, row0 = wid*16;
  ksLds[t] = ksumf[(size_t)bh*MPAD + t];
  if (t < 32) ksLds[256+t] = ksumf[(size_t)bh*MPAD + 256 + t];
  __syncthreads();

  f32x4 acc[18];
  #pragma unroll
  for (int c=0;c<18;c++) acc[c] = f32x4{0.f,0.f,0.f,0.f};
  const bf16_t* abase = qkv + ((size_t)(b*4096) + n0 + row0 + l15)*1536 + h*64;
  #pragma unroll
  for (int kh=0;kh<2;kh++){
    bf16x8 a = *(const bf16x8*)(abase + kh*32 + l4*8);
    #pragma unroll
    for (int ct=0;ct<18;ct++){
      bf16x8 bb = *(const bf16x8*)(pmb + (ct*16+l15)*64 + kh*32 + l4*8);
      acc[ct] = MFMA16(a, bb, acc[ct]);
    }
  }
  // per-row max over valid cols
  float mxr[4] = {-3e38f,-3e38f,-3e38f,-3e38f};
  #pragma unroll
  for (int ct=0;ct<18;ct++){
    if (ct*16 + l15 < 266){
      #pragma unroll
      for (int r=0;r<4;r++) mxr[r] = fmaxf(mxr[r], acc[ct][r]);
    }
  }
  #pragma unroll
  for (int r=0;r<4;r++){
    mxr[r] = fmaxf(mxr[r], __shfl_xor(mxr[r], 1));
    mxr[r] = fmaxf(mxr[r], __shfl_xor(mxr[r], 2));
    mxr[r] = fmaxf(mxr[r], __shfl_xor(mxr[r], 4));
    mxr[r] = fmaxf(mxr[r], __shfl_xor(mxr[r], 8));
  }
  float dg[4];
  #pragma unroll
  for (int r=0;r<4;r++) dg[r] = diagq[(size_t)bh*4096 + n0 + row0 + l4*4 + r];
  float den[4] = {0.f,0.f,0.f,0.f};
  #pragma unroll
  for (int ct=0;ct<18;ct++){
    int col = ct*16 + l15;
    float ks = ksLds[col];
    #pragma unroll
    for (int r=0;r<4;r++){
      float qpv = 0.f;
      if (col < 266){
        qpv = RATIO*(__expf(acc[ct][r] - dg[r] - mxr[r]) + KEPS);
        den[r] += qpv*ks;
      }
      qpLds[(row0 + l4*4 + r)*296 + col] = f2b(qpv);
    }
  }
  float dinv[4];
  #pragma unroll
  for (int r=0;r<4;r++){
    den[r] += __shfl_xor(den[r], 1);
    den[r] += __shfl_xor(den[r], 2);
    den[r] += __shfl_xor(den[r], 4);
    den[r] += __shfl_xor(den[r], 8);
    dinv[r] = 1.0f/den[r];
  }
  __syncthreads();

  f32x4 o2[4];
  #pragma unroll
  for (int c=0;c<4;c++) o2[c] = f32x4{0.f,0.f,0.f,0.f};
  const bf16_t* Bbase = ctxT + (size_t)bh*64*MPAD;
  #pragma unroll
  for (int kk=0;kk<9;kk++){
    int k0 = kk*32;
    bf16x8 a = *(const bf16x8*)&qpLds[(row0 + l15)*296 + k0 + l4*8];
    #pragma unroll
    for (int ct=0;ct<4;ct++){
      bf16x8 bb = *(const bf16x8*)(Bbase + (size_t)(ct*16+l15)*MPAD + k0 + l4*8);
      o2[ct] = MFMA16(a, bb, o2[ct]);
    }
  }
  #pragma unroll
  for (int ct=0;ct<4;ct++)
    #pragma unroll
    for (int r=0;r<4;r++)
      attn[((size_t)(b*4096) + n0 + row0 + l4*4 + r)*512 + h*64 + ct*16 + l15]
        = f2b(o2[ct][r] * dinv[r]);
}

// ---------------------------------------------------------------- launcher
extern "C" void kernel_launch(void* const* d_in, const int* in_sizes, int n_in,
                              void* d_out, int out_size, void* d_ws, size_t ws_size,
                              hipStream_t stream)
{
  (void)in_sizes; (void)n_in; (void)out_size;
  const float* x      = (const float*)d_in[0];
  const float* proj_w = (const float*)d_in[1];
  const float* proj_b = (const float*)d_in[2];
  const float* ln1_g  = (const float*)d_in[3];
  const float* ln1_b  = (const float*)d_in[4];
  const float* wq     = (const float*)d_in[5];
  const float* bq     = (const float*)d_in[6];
  const float* wk     = (const float*)d_in[7];
  const float* bk     = (const float*)d_in[8];
  const float* wv     = (const float*)d_in[9];
  const float* bv     = (const float*)d_in[10];
  const float* wo     = (const float*)d_in[11];
  const float* bo     = (const float*)d_in[12];
  const float* pm     = (const float*)d_in[13];
  const float* ln2_g  = (const float*)d_in[14];
  const float* ln2_b  = (const float*)d_in[15];
  const float* w1     = (const float*)d_in[16];
  const float* b1     = (const float*)d_in[17];
  const float* w2     = (const float*)d_in[18];
  const float* b2     = (const float*)d_in[19];
  float* out = (float*)d_out;
  const size_t MB = 1ull<<20;

  char* ws = (char*)d_ws;
  size_t off = 0;
  auto alloc = [&](size_t bytes)->void*{ void* p = ws + off; off += (bytes + 255) & ~(size_t)255; return p; };
  bf16_t* Wt_proj = (bf16_t*)alloc(2ul*1024*1024);
  bf16_t* Wt_qkv  = (bf16_t*)alloc(2ul*1536*1024);
  bf16_t* Wt_o    = (bf16_t*)alloc(2ul*1024*512);
  bf16_t* Wt_1    = (bf16_t*)alloc(2ul*4096*1024);
  bf16_t* Wt_2    = (bf16_t*)alloc(2ul*1024*4096);
  float*  bqkv    = (float*) alloc(4ul*1536);
  unsigned* mxk   = (unsigned*)alloc(4ul*32);
  bf16_t* pmb     = (bf16_t*)alloc(2ul*MPAD*64);
  float*  diagq   = (float*) alloc(4ul*32*4096);
  float*  diagk   = (float*) alloc(4ul*32*4096);
  float*  ksumf   = (float*) alloc(4ul*32*MPAD);
  bf16_t* ctxT    = (bf16_t*)alloc(2ul*32*64*MPAD);
  char*   R       = (char*)  alloc(0);
  size_t R_avail = (ws_size > off) ? ws_size - off : 0;

  // region floor: phase A 64MB, k-side KG=4 67MB, ff NC=4 50MB
  if (R_avail < 67*MB){ zero_out<<<dim3(65536), 256, 0, stream>>>(out, 16777216L); return; }
  int KG = (R_avail >= 87*MB) ? 8 : 4;    // k-side top: 48 + 2*KG*2.36MB
  int NC = (R_avail >= 84*MB) ? 2 : 4;    // ff top: 16 + (16384/NC)*8KB

  // R overlays (stream-serialized disjoint lifetimes)
  bf16_t* qkv  = (bf16_t*)(R);               // 48MB   [LN1/qkv .. favor_q]
  bf16_t* h1c  = (bf16_t*)(R + 48*MB);       // 16MB   [phase A]
  bf16_t* kp   = (bf16_t*)(R + 48*MB);       // KG*2.36MB [k-side]
  bf16_t* kpT  = (bf16_t*)(R + 48*MB + (size_t)KG*4096*MPAD*2 + 1*MB);
  bf16_t* attn = (bf16_t*)(R + 48*MB);       // 16MB   [favor_q .. wo]
  long    CH   = 16384/NC;
  bf16_t* h2c  = (bf16_t*)(R);               // 16MB/NC*2... reused as xbc too
  bf16_t* ff1c = (bf16_t*)(R + 16*MB);       // CH*8KB
  bf16_t* vT   = (bf16_t*)d_out;             // 16.8MB scratch in d_out (dead till wo)

  // 1) weights -> bf16 transposed, pm cast
  wt_cast<<<dim3(32,32), 256, 0, stream>>>(proj_w, Wt_proj, 1024, 1024);
  wt_cast<<<dim3(32,16), 256, 0, stream>>>(wq, Wt_qkv,              1024, 512);
  wt_cast<<<dim3(32,16), 256, 0, stream>>>(wk, Wt_qkv + 512*1024,   1024, 512);
  wt_cast<<<dim3(32,16), 256, 0, stream>>>(wv, Wt_qkv + 1024*1024,  1024, 512);
  wt_cast<<<dim3(16,32), 256, 0, stream>>>(wo, Wt_o, 512, 1024);
  wt_cast<<<dim3(32,128),256, 0, stream>>>(w1, Wt_1, 1024, 4096);
  wt_cast<<<dim3(128,32),256, 0, stream>>>(w2, Wt_2, 4096, 1024);
  concat_bias<<<dim3(6), 256, 0, stream>>>(bq, bk, bv, bqkv);
  pm_cast<<<dim3(72), 256, 0, stream>>>(pm, pmb);

  // 2) phase A: LN1 + qkv GEMM, 2 chunks of 8192 rows
  for (int c = 0; c < 2; c++){
    ln_kernel<<<dim3(8192), 256, 0, stream>>>(x + (size_t)c*8192*1024, ln1_g, ln1_b, h1c);
    gemm_bt<0,0,0,1><<<dim3(12,64), 256, 0, stream>>>(h1c, 1024, Wt_qkv, 1024,
        bqkv, nullptr, nullptr, qkv + (size_t)c*8192*1536, 1536, 1024);
  }

  // 3) FAVOR
  diag_kernel<<<dim3(16,32), 256, 0, stream>>>(qkv, diagq, diagk);
  vt_trans<<<dim3(128,64), 256, 0, stream>>>(qkv, vT);
  mx_init<<<dim3(1), 64, 0, stream>>>(mxk);
  favor_kmax2<<<dim3(64,32), 256, 0, stream>>>(qkv, pmb, mxk);
  for (int g = 0; g < 32; g += KG){
    favor_kp<<<dim3(64,KG), 256, 0, stream>>>(qkv, pmb, mxk, diagk, kp, g);
    trans_kp<<<dim3(128,9,KG), 256, 0, stream>>>(kp, kpT);
    ksum_kernel<<<dim3(KG*68), 256, 0, stream>>>(kpT, ksumf, g);
    ctx_gemm<<<dim3(17,KG), 256, 0, stream>>>(kpT, vT, ctxT, g);
  }
  favor_q<<<dim3(64,32), 256, 0, stream>>>(qkv, pmb, diagq, ksumf, ctxT, attn);

  // 4) x2 = x + attn @ wo + bo -> d_out (f32); overwrites vT scratch
  gemm_bt<1,0,0,0><<<dim3(8,128), 256, 0, stream>>>(attn, 512, Wt_o, 512,
      bo, x, nullptr, out, 1024, 512);

  // 5) per chunk: LN2 -> ff1(gelu) -> ff2(+res, in-place) -> gate(in-place)
  for (int c = 0; c < NC; c++){
    float* xrow = out + (size_t)c*CH*1024;
    ln_kernel<<<dim3((unsigned)CH), 256, 0, stream>>>(xrow, ln2_g, ln2_b, h2c);
    gemm_bt<0,1,0,1><<<dim3(32,(unsigned)(CH/128)), 256, 0, stream>>>(h2c, 1024, Wt_1, 1024,
        b1, nullptr, nullptr, ff1c, 4096, 1024);
    gemm_bt<1,0,0,0><<<dim3(8,(unsigned)(CH/128)), 256, 0, stream>>>(ff1c, 4096, Wt_2, 4096,
        b2, xrow, nullptr, xrow, 1024, 4096);
    cast_f32_bf16<<<dim3((unsigned)CH), 256, 0, stream>>>(x + (size_t)c*CH*1024, h2c);
    gemm_bt<0,0,1,0><<<dim3(8,(unsigned)(CH/128)), 256, 0, stream>>>(h2c, 1024, Wt_proj, 1024,
        proj_b, nullptr, xrow, xrow, 1024, 1024);
  }
}

// Round 4
// 1197.326 us; speedup vs baseline: 4.0912x; 1.0054x over previous
//
#include <hip/hip_runtime.h>
#include <math.h>

typedef unsigned short bf16_t;
using bf16x8 = __attribute__((ext_vector_type(8))) short;
using f32x4  = __attribute__((ext_vector_type(4))) float;

#define DEVFN static __device__ __forceinline__

DEVFN float b2f(bf16_t u){ unsigned v=((unsigned)u)<<16; float f; __builtin_memcpy(&f,&v,4); return f; }
DEVFN bf16_t f2b(float f){ unsigned u; __builtin_memcpy(&u,&f,4); u += 0x7fffu + ((u>>16)&1u); return (bf16_t)(u>>16); }
DEVFN unsigned encf(float f){ unsigned u=__float_as_uint(f); return (u&0x80000000u)? ~u : (u|0x80000000u); }
DEVFN float decf(unsigned e){ return __uint_as_float((e&0x80000000u)? (e^0x80000000u) : ~e); }

// erf via Abramowitz-Stegun 7.1.26, |abs err| <= 1.5e-7
DEVFN float erf_fast(float x){
  float ax = fabsf(x);
  float t = __builtin_amdgcn_rcpf(1.0f + 0.3275911f*ax);
  float y = t*(0.254829592f + t*(-0.284496736f + t*(1.421413741f
          + t*(-1.453152027f + t*1.061405429f))));
  float r = 1.0f - y*__expf(-ax*ax);
  return copysignf(r, x);
}

constexpr float DN_SCALE = 0.35355339059327373f;   // 64^-0.25
constexpr float RATIO    = 0.06131393394849658f;   // 266^-0.5
constexpr float KEPS     = 1e-4f;
#define MPAD 288   // 266 features padded to 9*32

#define GLOAD_LDS16(g, l) __builtin_amdgcn_global_load_lds( \
    (__attribute__((address_space(1))) void*)(g), \
    (__attribute__((address_space(3))) void*)(l), 16, 0, 0)

#define MFMA16(a,b,c) __builtin_amdgcn_mfma_f32_16x16x32_bf16(a,b,c,0,0,0)

// ------------------------------------------------ weight transpose + cast
__global__ __launch_bounds__(256)
void wt_cast(const float* __restrict__ W, bf16_t* __restrict__ Wt, int K, int N)
{
  __shared__ alignas(16) float ts[32][33];
  int t = threadIdx.x;
  int r = t>>3, c4 = (t&7)*4;
  int k0 = blockIdx.x*32, n0 = blockIdx.y*32;
  float4 v = *(const float4*)(W + (size_t)(k0+r)*N + n0 + c4);
  ts[r][c4+0]=v.x; ts[r][c4+1]=v.y; ts[r][c4+2]=v.z; ts[r][c4+3]=v.w;
  __syncthreads();
  ushort4 o;
  o.x = f2b(ts[c4+0][r]); o.y = f2b(ts[c4+1][r]);
  o.z = f2b(ts[c4+2][r]); o.w = f2b(ts[c4+3][r]);
  *(ushort4*)(Wt + (size_t)(n0+r)*K + k0 + c4) = o;
}

__global__ __launch_bounds__(256)
void concat_bias(const float* __restrict__ bq, const float* __restrict__ bk,
                 const float* __restrict__ bv, float* __restrict__ dst)
{
  int t = blockIdx.x*256 + threadIdx.x;
  if (t < 512) dst[t] = bq[t];
  else if (t < 1024) dst[t] = bk[t-512];
  else dst[t] = bv[t-1024];
}

__global__ void mx_init(unsigned* m){ if (threadIdx.x < 32) m[threadIdx.x] = 0u; }

__global__ void zero_out(float* o, long n){
  long i = (long)blockIdx.x*256 + threadIdx.x;
  if (i < n) o[i] = 0.f;
}

// pmb[m][64] bf16 = pm * dn, zero-padded rows 266..287
__global__ __launch_bounds__(256)
void pm_cast(const float* __restrict__ pm, bf16_t* __restrict__ pmb)
{
  int idx = blockIdx.x*256 + threadIdx.x;      // grid 72 -> 18432
  int r = idx>>6, c = idx&63;
  pmb[idx] = (r < 266) ? f2b(pm[r*64+c]*DN_SCALE) : (bf16_t)0;
}

// diag for q and k: 0.5*dn^2 * sum(d^2). grid (16, 32bh)
__global__ __launch_bounds__(256)
void diag_kernel(const bf16_t* __restrict__ qkv, float* __restrict__ diagq,
                 float* __restrict__ diagk)
{
  int bh = blockIdx.y, b = bh>>3, h = bh&7;
  int n = blockIdx.x*256 + threadIdx.x;
  long trow = (long)b*4096 + n;
  const bf16_t* qp_ = qkv + trow*1536 + h*64;
  const bf16_t* kp_ = qkv + trow*1536 + 512 + h*64;
  float sq = 0.f, sk = 0.f;
  #pragma unroll
  for (int i=0;i<8;i++){
    uint4 cq = ((const uint4*)qp_)[i];
    uint4 ck = ((const uint4*)kp_)[i];
    unsigned w[4] = {cq.x,cq.y,cq.z,cq.w};
    unsigned v[4] = {ck.x,ck.y,ck.z,ck.w};
    #pragma unroll
    for (int j=0;j<4;j++){
      float a0=b2f((bf16_t)(w[j]&0xffff)), a1=b2f((bf16_t)(w[j]>>16));
      float b0=b2f((bf16_t)(v[j]&0xffff)), b1=b2f((bf16_t)(v[j]>>16));
      sq += a0*a0 + a1*a1; sk += b0*b0 + b1*b1;
    }
  }
  float sc = 0.5f*DN_SCALE*DN_SCALE;
  diagq[(long)bh*4096 + n] = sq*sc;
  diagk[(long)bh*4096 + n] = sk*sc;
}

// v transpose: qkv v-part -> vT[bh*64+d][4096]. grid (128, 64), block 256
__global__ __launch_bounds__(256)
void vt_trans(const bf16_t* __restrict__ qkv, bf16_t* __restrict__ vT)
{
  __shared__ ushort ts[32][36];
  int by = blockIdx.y;
  int bh = by>>1, dt = by&1, b = bh>>3, h = bh&7;
  int n0 = blockIdx.x*32;
  int t = threadIdx.x, r = t>>3, c4 = (t&7)*4;
  ushort4 v = *(const ushort4*)(qkv + ((size_t)b*4096 + n0 + r)*1536 + 1024 + h*64 + dt*32 + c4);
  ts[r][c4+0]=v.x; ts[r][c4+1]=v.y; ts[r][c4+2]=v.z; ts[r][c4+3]=v.w;
  __syncthreads();
  ushort4 o;
  o.x = ts[c4+0][r]; o.y = ts[c4+1][r]; o.z = ts[c4+2][r]; o.w = ts[c4+3][r];
  *(ushort4*)(vT + ((size_t)bh*64 + dt*32 + r)*4096 + n0 + c4) = o;
}

// ---------------------------------------------------------------- LayerNorm
__global__ __launch_bounds__(256)
void ln_kernel(const float* __restrict__ x, const float* __restrict__ g,
               const float* __restrict__ b, bf16_t* __restrict__ out)
{
  long row = blockIdx.x; int t = threadIdx.x;
  float4 v = ((const float4*)x)[row*256 + t];
  float s = v.x+v.y+v.z+v.w;
  #pragma unroll
  for (int o=32;o>0;o>>=1) s += __shfl_xor(s, o);
  __shared__ float r1[4], r2[4];
  if ((t&63)==0) r1[t>>6] = s;
  __syncthreads();
  float mu = (r1[0]+r1[1]+r1[2]+r1[3]) * (1.f/1024.f);
  float dx = v.x-mu, dy = v.y-mu, dz = v.z-mu, dw = v.w-mu;
  float ss = dx*dx+dy*dy+dz*dz+dw*dw;
  #pragma unroll
  for (int o=32;o>0;o>>=1) ss += __shfl_xor(ss, o);
  if ((t&63)==0) r2[t>>6] = ss;
  __syncthreads();
  float var = (r2[0]+r2[1]+r2[2]+r2[3]) * (1.f/1024.f);
  float rs = rsqrtf(var + 1e-5f);
  float4 gg = ((const float4*)g)[t], bb = ((const float4*)b)[t];
  ushort4 o4;
  o4.x = f2b(dx*rs*gg.x+bb.x); o4.y = f2b(dy*rs*gg.y+bb.y);
  o4.z = f2b(dz*rs*gg.z+bb.z); o4.w = f2b(dw*rs*gg.w+bb.w);
  ((ushort4*)out)[row*256+t] = o4;
}

// f32 -> bf16 cast, grid = rows (of 1024)
__global__ __launch_bounds__(256)
void cast_f32_bf16(const float* __restrict__ in, bf16_t* __restrict__ out)
{
  long i = (long)blockIdx.x*256 + threadIdx.x;
  float4 v = ((const float4*)in)[i];
  ushort4 o;
  o.x = f2b(v.x); o.y = f2b(v.y); o.z = f2b(v.z); o.w = f2b(v.w);
  ((ushort4*)out)[i] = o;
}

// ---------------------------------------------------------------- GEMM (bf16 MFMA)
// 128x128 tile, BK=32, 4 waves. Block-index remap: bijective XCD chunking +
// 16-row supertile (ty-fast) for L2 locality on B panels. Requires NY%16==0,
// nwg%8==0 (all call sites satisfy).
template<int RES, int GELU, int GATEF, int OBF>
__global__ __launch_bounds__(256)
void gemm_bt(const bf16_t* __restrict__ A, int lda,
             const bf16_t* __restrict__ Bt, int ldb,
             const float* __restrict__ bias,
             const float* res,
             const float* gatef,
             void* Cout, int N, int K)
{
  __shared__ alignas(16) bf16_t As[128*32];
  __shared__ alignas(16) bf16_t Bs[128*32];
  const int tid = threadIdx.x;
  const int wid = tid>>6, lane = tid&63;
  const int l15 = lane&15, l4 = lane>>4;
  const int wm = wid>>1, wn = wid&1;

  // ---- block remap: XCD-contiguous chunks over a ty-fast supertiled order
  const int NX = gridDim.x;
  const int nwg = NX * gridDim.y;
  const int lid = blockIdx.y*NX + blockIdx.x;
  const int qc = nwg>>3;
  const int wgid = (lid&7)*qc + (lid>>3);          // nwg%8==0 bijective chunk
  const int stripe = wgid / (16*NX);
  const int rem    = wgid % (16*NX);
  const long m0 = (long)(stripe*16 + (rem & 15))*128;
  const long n0 = (long)(rem >> 4)*128;

  f32x4 acc[4][4];
  #pragma unroll
  for (int i=0;i<4;i++)
    #pragma unroll
    for (int j=0;j<4;j++) acc[i][j] = f32x4{0.f,0.f,0.f,0.f};

  const bf16_t* ga = A  + (size_t)(m0 + (tid>>2))*lda + (tid&3)*8;
  const bf16_t* gb = Bt + (size_t)(n0 + (tid>>2))*ldb + (tid&3)*8;
  bf16_t* lA0 = As + wid*512;
  bf16_t* lA1 = As + 2048 + wid*512;
  bf16_t* lB0 = Bs + wid*512;
  bf16_t* lB1 = Bs + 2048 + wid*512;

  for (int k0 = 0; k0 < K; k0 += 32){
    GLOAD_LDS16(ga,                   lA0);
    GLOAD_LDS16(ga + (size_t)64*lda,  lA1);
    GLOAD_LDS16(gb,                   lB0);
    GLOAD_LDS16(gb + (size_t)64*ldb,  lB1);
    ga += 32; gb += 32;
    __syncthreads();
    bf16x8 af[4], bfr[4];
    #pragma unroll
    for (int i=0;i<4;i++){
      af[i]  = *(const bf16x8*)(As + (wm*64 + i*16 + l15)*32 + l4*8);
      bfr[i] = *(const bf16x8*)(Bs + (wn*64 + i*16 + l15)*32 + l4*8);
    }
    #pragma unroll
    for (int i=0;i<4;i++)
      #pragma unroll
      for (int j=0;j<4;j++)
        acc[i][j] = MFMA16(af[i], bfr[j], acc[i][j]);
    __syncthreads();
  }

  #pragma unroll
  for (int i=0;i<4;i++){
    #pragma unroll
    for (int j=0;j<4;j++){
      #pragma unroll
      for (int r=0;r<4;r++){
        long row = m0 + wm*64 + i*16 + l4*4 + r;
        long col = n0 + wn*64 + j*16 + l15;
        float v = acc[i][j][r] + bias[col];
        if constexpr (RES)   v += res[row*(long)N + col];
        if constexpr (GELU)  v = 0.5f*v*(1.0f + erf_fast(v*0.70710678118654752f));
        if constexpr (GATEF) v *= gatef[row*(long)N + col];
        if constexpr (OBF)  ((bf16_t*)Cout)[row*(long)N + col] = f2b(v);
        else                ((float* )Cout)[row*(long)N + col] = v;
      }
    }
  }
}

// ---------------------------------------------------------------- FAVOR (MFMA)
// qkv: [16384][1536] bf16, q @ h*64, k @ 512+h*64, v @ 1024+h*64.

// dd-max over all (n,m) per bh. grid (64, 32), block 256 (4 waves x 16 rows)
__global__ __launch_bounds__(256,2)
void favor_kmax2(const bf16_t* __restrict__ qkv, const bf16_t* __restrict__ pmb,
                 unsigned* __restrict__ mxk)
{
  int bh = blockIdx.y, b = bh>>3, h = bh&7;
  int t = threadIdx.x, wid = t>>6, lane = t&63;
  int l15 = lane&15, l4 = lane>>4;
  int n0 = blockIdx.x*64, row0 = wid*16;
  f32x4 acc[18];
  #pragma unroll
  for (int c=0;c<18;c++) acc[c] = f32x4{0.f,0.f,0.f,0.f};
  const bf16_t* abase = qkv + ((size_t)(b*4096) + n0 + row0 + l15)*1536 + 512 + h*64;
  #pragma unroll
  for (int kh=0;kh<2;kh++){
    bf16x8 a = *(const bf16x8*)(abase + kh*32 + l4*8);
    #pragma unroll
    for (int ct=0;ct<18;ct++){
      bf16x8 bb = *(const bf16x8*)(pmb + (ct*16+l15)*64 + kh*32 + l4*8);
      acc[ct] = MFMA16(a, bb, acc[ct]);
    }
  }
  float mx = -3e38f;
  #pragma unroll
  for (int ct=0;ct<18;ct++){
    if (ct*16 + l15 < 266){
      #pragma unroll
      for (int r=0;r<4;r++) mx = fmaxf(mx, acc[ct][r]);
    }
  }
  #pragma unroll
  for (int o=32;o>0;o>>=1) mx = fmaxf(mx, __shfl_xor(mx, o));
  __shared__ float red[4];
  if (lane==0) red[wid] = mx;
  __syncthreads();
  if (t==0){
    float m2 = fmaxf(fmaxf(red[0],red[1]),fmaxf(red[2],red[3]));
    atomicMax(mxk + bh, encf(m2));
  }
}

// kp = ratio*(exp(dd - diag - MX)+eps) -> kp[bhl][n][MPAD]. grid (64, KG)
__global__ __launch_bounds__(256,2)
void favor_kp(const bf16_t* __restrict__ qkv, const bf16_t* __restrict__ pmb,
              const unsigned* __restrict__ mxk, const float* __restrict__ diagk,
              bf16_t* __restrict__ kp, int bh0)
{
  int bhl = blockIdx.y, bh = bh0 + bhl, b = bh>>3, h = bh&7;
  int t = threadIdx.x, wid = t>>6, lane = t&63;
  int l15 = lane&15, l4 = lane>>4;
  int n0 = blockIdx.x*64, row0 = wid*16;
  f32x4 acc[18];
  #pragma unroll
  for (int c=0;c<18;c++) acc[c] = f32x4{0.f,0.f,0.f,0.f};
  const bf16_t* abase = qkv + ((size_t)(b*4096) + n0 + row0 + l15)*1536 + 512 + h*64;
  #pragma unroll
  for (int kh=0;kh<2;kh++){
    bf16x8 a = *(const bf16x8*)(abase + kh*32 + l4*8);
    #pragma unroll
    for (int ct=0;ct<18;ct++){
      bf16x8 bb = *(const bf16x8*)(pmb + (ct*16+l15)*64 + kh*32 + l4*8);
      acc[ct] = MFMA16(a, bb, acc[ct]);
    }
  }
  float MX = decf(mxk[bh]);
  float dg[4];
  #pragma unroll
  for (int r=0;r<4;r++) dg[r] = diagk[(size_t)bh*4096 + n0 + row0 + l4*4 + r];
  #pragma unroll
  for (int ct=0;ct<18;ct++){
    int col = ct*16 + l15;
    #pragma unroll
    for (int r=0;r<4;r++){
      float v = (col < 266) ? RATIO*(__expf(acc[ct][r] - dg[r] - MX) + KEPS) : 0.f;
      kp[((size_t)bhl*4096 + n0 + row0 + l4*4 + r)*MPAD + col] = f2b(v);
    }
  }
}

// kp [bhl][4096][MPAD] -> kpT [bhl][MPAD][4096]. grid (128, 9, KG)
__global__ __launch_bounds__(256)
void trans_kp(const bf16_t* __restrict__ kp, bf16_t* __restrict__ kpT)
{
  __shared__ ushort ts[32][36];
  int bhl = blockIdx.z;
  int n0 = blockIdx.x*32, m0 = blockIdx.y*32;
  int t = threadIdx.x, r = t>>3, c4 = (t&7)*4;
  ushort4 v = *(const ushort4*)(kp + ((size_t)bhl*4096 + n0 + r)*MPAD + m0 + c4);
  ts[r][c4+0]=v.x; ts[r][c4+1]=v.y; ts[r][c4+2]=v.z; ts[r][c4+3]=v.w;
  __syncthreads();
  ushort4 o;
  o.x = ts[c4+0][r]; o.y = ts[c4+1][r]; o.z = ts[c4+2][r]; o.w = ts[c4+3][r];
  *(ushort4*)(kpT + ((size_t)bhl*MPAD + m0 + r)*4096 + n0 + c4) = o;
}

// ksum[m] = sum_n kp. one wave per m-row. grid (KG*68)
__global__ __launch_bounds__(256)
void ksum_kernel(const bf16_t* __restrict__ kpT, float* __restrict__ ksumf, int bh0)
{
  int t = threadIdx.x, wid = t>>6, lane = t&63;
  int rr = blockIdx.x*4 + wid;
  int bhl = rr/272, m = rr%272;
  const bf16_t* row = kpT + ((size_t)bhl*MPAD + m)*4096;
  float s = 0.f;
  #pragma unroll
  for (int j=0;j<8;j++){
    bf16x8 v = *(const bf16x8*)(row + j*512 + lane*8);
    #pragma unroll
    for (int e=0;e<8;e++) s += b2f((bf16_t)v[e]);
  }
  #pragma unroll
  for (int o=32;o>0;o>>=1) s += __shfl_xor(s, o);
  if (lane==0) ksumf[(size_t)(bh0+bhl)*MPAD + m] = s;
}

// ctx GEMM: ctxT[bh][d][m] = sum_n kpT[m][n]*vT[d][n]. grid (17, KG)
__global__ __launch_bounds__(256,2)
void ctx_gemm(const bf16_t* __restrict__ kpT, const bf16_t* __restrict__ vT,
              bf16_t* __restrict__ ctxT, int bh0)
{
  int bhl = blockIdx.y, bh = bh0 + bhl;
  int t = threadIdx.x, wid = t>>6, lane = t&63;
  int l15 = lane&15, l4 = lane>>4;
  int m0 = blockIdx.x*16;
  f32x4 acc[4];
  #pragma unroll
  for (int c=0;c<4;c++) acc[c] = f32x4{0.f,0.f,0.f,0.f};
  const bf16_t* Abase = kpT + ((size_t)bhl*MPAD + m0 + l15)*4096;
  const bf16_t* Bbase = vT + ((size_t)bh*64)*4096;
  for (int k = wid*1024; k < wid*1024 + 1024; k += 32){
    bf16x8 a = *(const bf16x8*)(Abase + k + l4*8);
    #pragma unroll
    for (int ct=0;ct<4;ct++){
      bf16x8 bb = *(const bf16x8*)(Bbase + (size_t)(ct*16+l15)*4096 + k + l4*8);
      acc[ct] = MFMA16(a, bb, acc[ct]);
    }
  }
  __shared__ float red[4][4][16][16];
  #pragma unroll
  for (int ct=0;ct<4;ct++)
    #pragma unroll
    for (int r=0;r<4;r++) red[wid][ct][l4*4+r][l15] = acc[ct][r];
  __syncthreads();
  #pragma unroll
  for (int i=0;i<4;i++){
    int e = i*256 + t;
    int ct = e>>8, row = (e>>4)&15, col = e&15;
    float s = ((red[0][ct][row][col] + red[1][ct][row][col])
             + (red[2][ct][row][col] + red[3][ct][row][col]));
    ctxT[((size_t)bh*64 + ct*16 + col)*MPAD + m0 + row] = f2b(s);
  }
}

// fused q-side: dd MFMA -> rowmax -> qp -> LDS -> out MFMA * dinv -> attn
// grid (64, 32), block 256 (4 waves x 16 rows)
__global__ __launch_bounds__(256,2)
void favor_q(const bf16_t* __restrict__ qkv, const bf16_t* __restrict__ pmb,
             const float* __restrict__ diagq, const float* __restrict__ ksumf,
             const bf16_t* __restrict__ ctxT, bf16_t* __restrict__ attn)
{
  __shared__ alignas(16) ushort qpLds[64*296];
  __shared__ float ksLds[288];
  int bh = blockIdx.y, b = bh>>3, h = bh&7;
  int t = threadIdx.x, wid = t>>6, lane = t&63;
  int l15 = lane&15, l4 = lane>>4;
  int n0 = blockIdx.x*64, row0 = wid*16;
  ksLds[t] = ksumf[(size_t)bh*MPAD + t];
  if (t < 32) ksLds[256+t] = ksumf[(size_t)bh*MPAD + 256 + t];
  __syncthreads();

  f32x4 acc[18];
  #pragma unroll
  for (int c=0;c<18;c++) acc[c] = f32x4{0.f,0.f,0.f,0.f};
  const bf16_t* abase = qkv + ((size_t)(b*4096) + n0 + row0 + l15)*1536 + h*64;
  #pragma unroll
  for (int kh=0;kh<2;kh++){
    bf16x8 a = *(const bf16x8*)(abase + kh*32 + l4*8);
    #pragma unroll
    for (int ct=0;ct<18;ct++){
      bf16x8 bb = *(const bf16x8*)(pmb + (ct*16+l15)*64 + kh*32 + l4*8);
      acc[ct] = MFMA16(a, bb, acc[ct]);
    }
  }
  // per-row max over valid cols
  float mxr[4] = {-3e38f,-3e38f,-3e38f,-3e38f};
  #pragma unroll
  for (int ct=0;ct<18;ct++){
    if (ct*16 + l15 < 266){
      #pragma unroll
      for (int r=0;r<4;r++) mxr[r] = fmaxf(mxr[r], acc[ct][r]);
    }
  }
  #pragma unroll
  for (int r=0;r<4;r++){
    mxr[r] = fmaxf(mxr[r], __shfl_xor(mxr[r], 1));
    mxr[r] = fmaxf(mxr[r], __shfl_xor(mxr[r], 2));
    mxr[r] = fmaxf(mxr[r], __shfl_xor(mxr[r], 4));
    mxr[r] = fmaxf(mxr[r], __shfl_xor(mxr[r], 8));
  }
  float dg[4];
  #pragma unroll
  for (int r=0;r<4;r++) dg[r] = diagq[(size_t)bh*4096 + n0 + row0 + l4*4 + r];
  float den[4] = {0.f,0.f,0.f,0.f};
  #pragma unroll
  for (int ct=0;ct<18;ct++){
    int col = ct*16 + l15;
    float ks = ksLds[col];
    #pragma unroll
    for (int r=0;r<4;r++){
      float qpv = 0.f;
      if (col < 266){
        qpv = RATIO*(__expf(acc[ct][r] - dg[r] - mxr[r]) + KEPS);
        den[r] += qpv*ks;
      }
      qpLds[(row0 + l4*4 + r)*296 + col] = f2b(qpv);
    }
  }
  float dinv[4];
  #pragma unroll
  for (int r=0;r<4;r++){
    den[r] += __shfl_xor(den[r], 1);
    den[r] += __shfl_xor(den[r], 2);
    den[r] += __shfl_xor(den[r], 4);
    den[r] += __shfl_xor(den[r], 8);
    dinv[r] = 1.0f/den[r];
  }
  __syncthreads();

  f32x4 o2[4];
  #pragma unroll
  for (int c=0;c<4;c++) o2[c] = f32x4{0.f,0.f,0.f,0.f};
  const bf16_t* Bbase = ctxT + (size_t)bh*64*MPAD;
  #pragma unroll
  for (int kk=0;kk<9;kk++){
    int k0 = kk*32;
    bf16x8 a = *(const bf16x8*)&qpLds[(row0 + l15)*296 + k0 + l4*8];
    #pragma unroll
    for (int ct=0;ct<4;ct++){
      bf16x8 bb = *(const bf16x8*)(Bbase + (size_t)(ct*16+l15)*MPAD + k0 + l4*8);
      o2[ct] = MFMA16(a, bb, o2[ct]);
    }
  }
  #pragma unroll
  for (int ct=0;ct<4;ct++)
    #pragma unroll
    for (int r=0;r<4;r++)
      attn[((size_t)(b*4096) + n0 + row0 + l4*4 + r)*512 + h*64 + ct*16 + l15]
        = f2b(o2[ct][r] * dinv[r]);
}

// ---------------------------------------------------------------- launcher
extern "C" void kernel_launch(void* const* d_in, const int* in_sizes, int n_in,
                              void* d_out, int out_size, void* d_ws, size_t ws_size,
                              hipStream_t stream)
{
  (void)in_sizes; (void)n_in; (void)out_size;
  const float* x      = (const float*)d_in[0];
  const float* proj_w = (const float*)d_in[1];
  const float* proj_b = (const float*)d_in[2];
  const float* ln1_g  = (const float*)d_in[3];
  const float* ln1_b  = (const float*)d_in[4];
  const float* wq     = (const float*)d_in[5];
  const float* bq     = (const float*)d_in[6];
  const float* wk     = (const float*)d_in[7];
  const float* bk     = (const float*)d_in[8];
  const float* wv     = (const float*)d_in[9];
  const float* bv     = (const float*)d_in[10];
  const float* wo     = (const float*)d_in[11];
  const float* bo     = (const float*)d_in[12];
  const float* pm     = (const float*)d_in[13];
  const float* ln2_g  = (const float*)d_in[14];
  const float* ln2_b  = (const float*)d_in[15];
  const float* w1     = (const float*)d_in[16];
  const float* b1     = (const float*)d_in[17];
  const float* w2     = (const float*)d_in[18];
  const float* b2     = (const float*)d_in[19];
  float* out = (float*)d_out;
  const size_t MB = 1ull<<20;

  char* ws = (char*)d_ws;
  size_t off = 0;
  auto alloc = [&](size_t bytes)->void*{ void* p = ws + off; off += (bytes + 255) & ~(size_t)255; return p; };
  bf16_t* Wt_proj = (bf16_t*)alloc(2ul*1024*1024);
  bf16_t* Wt_qkv  = (bf16_t*)alloc(2ul*1536*1024);
  bf16_t* Wt_o    = (bf16_t*)alloc(2ul*1024*512);
  bf16_t* Wt_1    = (bf16_t*)alloc(2ul*4096*1024);
  bf16_t* Wt_2    = (bf16_t*)alloc(2ul*1024*4096);
  float*  bqkv    = (float*) alloc(4ul*1536);
  unsigned* mxk   = (unsigned*)alloc(4ul*32);
  bf16_t* pmb     = (bf16_t*)alloc(2ul*MPAD*64);
  float*  diagq   = (float*) alloc(4ul*32*4096);
  float*  diagk   = (float*) alloc(4ul*32*4096);
  float*  ksumf   = (float*) alloc(4ul*32*MPAD);
  bf16_t* ctxT    = (bf16_t*)alloc(2ul*32*64*MPAD);
  char*   R       = (char*)  alloc(0);
  size_t R_avail = (ws_size > off) ? ws_size - off : 0;

  // region floor: phase A 64MB, k-side KG=4 67MB, ff NC=4 50MB
  if (R_avail < 67*MB){ zero_out<<<dim3(65536), 256, 0, stream>>>(out, 16777216L); return; }
  int KG = (R_avail >= 87*MB) ? 8 : 4;    // k-side top: 48 + 2*KG*2.36MB
  int NC = (R_avail >= 84*MB) ? 2 : 4;    // ff top: 16 + (16384/NC)*8KB

  // R overlays (stream-serialized disjoint lifetimes)
  bf16_t* qkv  = (bf16_t*)(R);               // 48MB   [LN1/qkv .. favor_q]
  bf16_t* h1c  = (bf16_t*)(R + 48*MB);       // 16MB   [phase A]
  bf16_t* kp   = (bf16_t*)(R + 48*MB);       // KG*2.36MB [k-side]
  bf16_t* kpT  = (bf16_t*)(R + 48*MB + (size_t)KG*4096*MPAD*2 + 1*MB);
  bf16_t* attn = (bf16_t*)(R + 48*MB);       // 16MB   [favor_q .. wo]
  long    CH   = 16384/NC;
  bf16_t* h2c  = (bf16_t*)(R);               // reused as xbc too
  bf16_t* ff1c = (bf16_t*)(R + 16*MB);       // CH*8KB
  bf16_t* vT   = (bf16_t*)d_out;             // 16.8MB scratch in d_out (dead till wo)

  // 1) weights -> bf16 transposed, pm cast
  wt_cast<<<dim3(32,32), 256, 0, stream>>>(proj_w, Wt_proj, 1024, 1024);
  wt_cast<<<dim3(32,16), 256, 0, stream>>>(wq, Wt_qkv,              1024, 512);
  wt_cast<<<dim3(32,16), 256, 0, stream>>>(wk, Wt_qkv + 512*1024,   1024, 512);
  wt_cast<<<dim3(32,16), 256, 0, stream>>>(wv, Wt_qkv + 1024*1024,  1024, 512);
  wt_cast<<<dim3(16,32), 256, 0, stream>>>(wo, Wt_o, 512, 1024);
  wt_cast<<<dim3(32,128),256, 0, stream>>>(w1, Wt_1, 1024, 4096);
  wt_cast<<<dim3(128,32),256, 0, stream>>>(w2, Wt_2, 4096, 1024);
  concat_bias<<<dim3(6), 256, 0, stream>>>(bq, bk, bv, bqkv);
  pm_cast<<<dim3(72), 256, 0, stream>>>(pm, pmb);

  // 2) phase A: LN1 + qkv GEMM, 2 chunks of 8192 rows
  for (int c = 0; c < 2; c++){
    ln_kernel<<<dim3(8192), 256, 0, stream>>>(x + (size_t)c*8192*1024, ln1_g, ln1_b, h1c);
    gemm_bt<0,0,0,1><<<dim3(12,64), 256, 0, stream>>>(h1c, 1024, Wt_qkv, 1024,
        bqkv, nullptr, nullptr, qkv + (size_t)c*8192*1536, 1536, 1024);
  }

  // 3) FAVOR
  diag_kernel<<<dim3(16,32), 256, 0, stream>>>(qkv, diagq, diagk);
  vt_trans<<<dim3(128,64), 256, 0, stream>>>(qkv, vT);
  mx_init<<<dim3(1), 64, 0, stream>>>(mxk);
  favor_kmax2<<<dim3(64,32), 256, 0, stream>>>(qkv, pmb, mxk);
  for (int g = 0; g < 32; g += KG){
    favor_kp<<<dim3(64,KG), 256, 0, stream>>>(qkv, pmb, mxk, diagk, kp, g);
    trans_kp<<<dim3(128,9,KG), 256, 0, stream>>>(kp, kpT);
    ksum_kernel<<<dim3(KG*68), 256, 0, stream>>>(kpT, ksumf, g);
    ctx_gemm<<<dim3(17,KG), 256, 0, stream>>>(kpT, vT, ctxT, g);
  }
  favor_q<<<dim3(64,32), 256, 0, stream>>>(qkv, pmb, diagq, ksumf, ctxT, attn);

  // 4) x2 = x + attn @ wo + bo -> d_out (f32); overwrites vT scratch
  gemm_bt<1,0,0,0><<<dim3(8,128), 256, 0, stream>>>(attn, 512, Wt_o, 512,
      bo, x, nullptr, out, 1024, 512);

  // 5) per chunk: LN2 -> ff1(gelu) -> ff2(+res, in-place) -> gate(in-place)
  for (int c = 0; c < NC; c++){
    float* xrow = out + (size_t)c*CH*1024;
    ln_kernel<<<dim3((unsigned)CH), 256, 0, stream>>>(xrow, ln2_g, ln2_b, h2c);
    gemm_bt<0,1,0,1><<<dim3(32,(unsigned)(CH/128)), 256, 0, stream>>>(h2c, 1024, Wt_1, 1024,
        b1, nullptr, nullptr, ff1c, 4096, 1024);
    gemm_bt<1,0,0,0><<<dim3(8,(unsigned)(CH/128)), 256, 0, stream>>>(ff1c, 4096, Wt_2, 4096,
        b2, xrow, nullptr, xrow, 1024, 4096);
    cast_f32_bf16<<<dim3((unsigned)CH), 256, 0, stream>>>(x + (size_t)c*CH*1024, h2c);
    gemm_bt<0,0,1,0><<<dim3(8,(unsigned)(CH/128)), 256, 0, stream>>>(h2c, 1024, Wt_proj, 1024,
        proj_b, nullptr, xrow, xrow, 1024, 1024);
  }
}

// Round 5
// 1056.144 us; speedup vs baseline: 4.6381x; 1.1337x over previous
//
#include <hip/hip_runtime.h>
#include <math.h>

typedef unsigned short bf16_t;
using bf16x8 = __attribute__((ext_vector_type(8))) short;
using f32x4  = __attribute__((ext_vector_type(4))) float;

#define DEVFN static __device__ __forceinline__

DEVFN float b2f(bf16_t u){ unsigned v=((unsigned)u)<<16; float f; __builtin_memcpy(&f,&v,4); return f; }
DEVFN bf16_t f2b(float f){ unsigned u; __builtin_memcpy(&u,&f,4); u += 0x7fffu + ((u>>16)&1u); return (bf16_t)(u>>16); }
DEVFN unsigned encf(float f){ unsigned u=__float_as_uint(f); return (u&0x80000000u)? ~u : (u|0x80000000u); }
DEVFN float decf(unsigned e){ return __uint_as_float((e&0x80000000u)? (e^0x80000000u) : ~e); }

// erf via Abramowitz-Stegun 7.1.26, |abs err| <= 1.5e-7
DEVFN float erf_fast(float x){
  float ax = fabsf(x);
  float t = __builtin_amdgcn_rcpf(1.0f + 0.3275911f*ax);
  float y = t*(0.254829592f + t*(-0.284496736f + t*(1.421413741f
          + t*(-1.453152027f + t*1.061405429f))));
  float r = 1.0f - y*__expf(-ax*ax);
  return copysignf(r, x);
}

constexpr float DN_SCALE = 0.35355339059327373f;   // 64^-0.25
constexpr float RATIO    = 0.06131393394849658f;   // 266^-0.5
constexpr float KEPS     = 1e-4f;
#define MPAD 288   // 266 features padded to 9*32

#define GLOAD_LDS16(g, l) __builtin_amdgcn_global_load_lds( \
    (__attribute__((address_space(1))) void*)(g), \
    (__attribute__((address_space(3))) void*)(l), 16, 0, 0)

#define MFMA16(a,b,c) __builtin_amdgcn_mfma_f32_16x16x32_bf16(a,b,c,0,0,0)

// ------------------------------------------------ weight transpose + cast
__global__ __launch_bounds__(256)
void wt_cast(const float* __restrict__ W, bf16_t* __restrict__ Wt, int K, int N)
{
  __shared__ alignas(16) float ts[32][33];
  int t = threadIdx.x;
  int r = t>>3, c4 = (t&7)*4;
  int k0 = blockIdx.x*32, n0 = blockIdx.y*32;
  float4 v = *(const float4*)(W + (size_t)(k0+r)*N + n0 + c4);
  ts[r][c4+0]=v.x; ts[r][c4+1]=v.y; ts[r][c4+2]=v.z; ts[r][c4+3]=v.w;
  __syncthreads();
  ushort4 o;
  o.x = f2b(ts[c4+0][r]); o.y = f2b(ts[c4+1][r]);
  o.z = f2b(ts[c4+2][r]); o.w = f2b(ts[c4+3][r]);
  *(ushort4*)(Wt + (size_t)(n0+r)*K + k0 + c4) = o;
}

__global__ __launch_bounds__(256)
void concat_bias(const float* __restrict__ bq, const float* __restrict__ bk,
                 const float* __restrict__ bv, float* __restrict__ dst)
{
  int t = blockIdx.x*256 + threadIdx.x;
  if (t < 512) dst[t] = bq[t];
  else if (t < 1024) dst[t] = bk[t-512];
  else dst[t] = bv[t-1024];
}

__global__ void mx_init(unsigned* m){ if (threadIdx.x < 32) m[threadIdx.x] = 0u; }

__global__ void zero_out(float* o, long n){
  long i = (long)blockIdx.x*256 + threadIdx.x;
  if (i < n) o[i] = 0.f;
}

// pmb[m][64] bf16 = pm * dn, zero-padded rows 266..287
__global__ __launch_bounds__(256)
void pm_cast(const float* __restrict__ pm, bf16_t* __restrict__ pmb)
{
  int idx = blockIdx.x*256 + threadIdx.x;      // grid 72 -> 18432
  int r = idx>>6, c = idx&63;
  pmb[idx] = (r < 266) ? f2b(pm[r*64+c]*DN_SCALE) : (bf16_t)0;
}

// diag for q and k: 0.5*dn^2 * sum(d^2). grid (16, 32bh)
__global__ __launch_bounds__(256)
void diag_kernel(const bf16_t* __restrict__ qkv, float* __restrict__ diagq,
                 float* __restrict__ diagk)
{
  int bh = blockIdx.y, b = bh>>3, h = bh&7;
  int n = blockIdx.x*256 + threadIdx.x;
  long trow = (long)b*4096 + n;
  const bf16_t* qp_ = qkv + trow*1536 + h*64;
  const bf16_t* kp_ = qkv + trow*1536 + 512 + h*64;
  float sq = 0.f, sk = 0.f;
  #pragma unroll
  for (int i=0;i<8;i++){
    uint4 cq = ((const uint4*)qp_)[i];
    uint4 ck = ((const uint4*)kp_)[i];
    unsigned w[4] = {cq.x,cq.y,cq.z,cq.w};
    unsigned v[4] = {ck.x,ck.y,ck.z,ck.w};
    #pragma unroll
    for (int j=0;j<4;j++){
      float a0=b2f((bf16_t)(w[j]&0xffff)), a1=b2f((bf16_t)(w[j]>>16));
      float b0=b2f((bf16_t)(v[j]&0xffff)), b1=b2f((bf16_t)(v[j]>>16));
      sq += a0*a0 + a1*a1; sk += b0*b0 + b1*b1;
    }
  }
  float sc = 0.5f*DN_SCALE*DN_SCALE;
  diagq[(long)bh*4096 + n] = sq*sc;
  diagk[(long)bh*4096 + n] = sk*sc;
}

// v transpose: qkv v-part -> vT[bh*64+d][4096]. grid (128, 64), block 256
__global__ __launch_bounds__(256)
void vt_trans(const bf16_t* __restrict__ qkv, bf16_t* __restrict__ vT)
{
  __shared__ ushort ts[32][36];
  int by = blockIdx.y;
  int bh = by>>1, dt = by&1, b = bh>>3, h = bh&7;
  int n0 = blockIdx.x*32;
  int t = threadIdx.x, r = t>>3, c4 = (t&7)*4;
  ushort4 v = *(const ushort4*)(qkv + ((size_t)b*4096 + n0 + r)*1536 + 1024 + h*64 + dt*32 + c4);
  ts[r][c4+0]=v.x; ts[r][c4+1]=v.y; ts[r][c4+2]=v.z; ts[r][c4+3]=v.w;
  __syncthreads();
  ushort4 o;
  o.x = ts[c4+0][r]; o.y = ts[c4+1][r]; o.z = ts[c4+2][r]; o.w = ts[c4+3][r];
  *(ushort4*)(vT + ((size_t)bh*64 + dt*32 + r)*4096 + n0 + c4) = o;
}

// ---------------------------------------------------------------- LayerNorm
__global__ __launch_bounds__(256)
void ln_kernel(const float* __restrict__ x, const float* __restrict__ g,
               const float* __restrict__ b, bf16_t* __restrict__ out)
{
  long row = blockIdx.x; int t = threadIdx.x;
  float4 v = ((const float4*)x)[row*256 + t];
  float s = v.x+v.y+v.z+v.w;
  #pragma unroll
  for (int o=32;o>0;o>>=1) s += __shfl_xor(s, o);
  __shared__ float r1[4], r2[4];
  if ((t&63)==0) r1[t>>6] = s;
  __syncthreads();
  float mu = (r1[0]+r1[1]+r1[2]+r1[3]) * (1.f/1024.f);
  float dx = v.x-mu, dy = v.y-mu, dz = v.z-mu, dw = v.w-mu;
  float ss = dx*dx+dy*dy+dz*dz+dw*dw;
  #pragma unroll
  for (int o=32;o>0;o>>=1) ss += __shfl_xor(ss, o);
  if ((t&63)==0) r2[t>>6] = ss;
  __syncthreads();
  float var = (r2[0]+r2[1]+r2[2]+r2[3]) * (1.f/1024.f);
  float rs = rsqrtf(var + 1e-5f);
  float4 gg = ((const float4*)g)[t], bb = ((const float4*)b)[t];
  ushort4 o4;
  o4.x = f2b(dx*rs*gg.x+bb.x); o4.y = f2b(dy*rs*gg.y+bb.y);
  o4.z = f2b(dz*rs*gg.z+bb.z); o4.w = f2b(dw*rs*gg.w+bb.w);
  ((ushort4*)out)[row*256+t] = o4;
}

// f32 -> bf16 cast, grid = rows (of 1024)
__global__ __launch_bounds__(256)
void cast_f32_bf16(const float* __restrict__ in, bf16_t* __restrict__ out)
{
  long i = (long)blockIdx.x*256 + threadIdx.x;
  float4 v = ((const float4*)in)[i];
  ushort4 o;
  o.x = f2b(v.x); o.y = f2b(v.y); o.z = f2b(v.z); o.w = f2b(v.w);
  ((ushort4*)out)[i] = o;
}

// ---------------------------------------------------------------- GEMM (bf16 MFMA)
// 128x128 tile, BK=32, 4 waves, double-buffered LDS (T3 minimum 2-phase:
// stage tile t+1 BEFORE computing tile t; one barrier per step). XCD-bijective
// chunking + 16-row supertile block remap for L2 locality (requires nwg%8==0).
template<int RES, int GELU, int GATEF, int OBF>
__global__ __launch_bounds__(256)
void gemm_bt(const bf16_t* __restrict__ A, int lda,
             const bf16_t* __restrict__ Bt, int ldb,
             const float* __restrict__ bias,
             const float* res,
             const float* gatef,
             void* Cout, int N, int K)
{
  __shared__ alignas(16) bf16_t As[2][128*32];
  __shared__ alignas(16) bf16_t Bs[2][128*32];
  const int tid = threadIdx.x;
  const int wid = tid>>6, lane = tid&63;
  const int l15 = lane&15, l4 = lane>>4;
  const int wm = wid>>1, wn = wid&1;

  // ---- block remap: XCD-contiguous chunks over a ty-fast supertiled order
  const int NX = gridDim.x;
  const int nwg = NX * gridDim.y;
  const int lid = blockIdx.y*NX + blockIdx.x;
  const int qc = nwg>>3;
  const int wgid = (lid&7)*qc + (lid>>3);          // nwg%8==0 bijective chunk
  const int stripe = wgid / (16*NX);
  const int rem    = wgid % (16*NX);
  const long m0 = (long)(stripe*16 + (rem & 15))*128;
  const long n0 = (long)(rem >> 4)*128;

  f32x4 acc[4][4];
  #pragma unroll
  for (int i=0;i<4;i++)
    #pragma unroll
    for (int j=0;j<4;j++) acc[i][j] = f32x4{0.f,0.f,0.f,0.f};

  const bf16_t* ga = A  + (size_t)(m0 + (tid>>2))*lda + (tid&3)*8;
  const bf16_t* gb = Bt + (size_t)(n0 + (tid>>2))*ldb + (tid&3)*8;

  auto STAGE = [&](int buf){
    GLOAD_LDS16(ga,                   &As[buf][wid*512]);
    GLOAD_LDS16(ga + (size_t)64*lda,  &As[buf][2048 + wid*512]);
    GLOAD_LDS16(gb,                   &Bs[buf][wid*512]);
    GLOAD_LDS16(gb + (size_t)64*ldb,  &Bs[buf][2048 + wid*512]);
    ga += 32; gb += 32;
  };

  const int nt = K >> 5;
  STAGE(0);
  __syncthreads();                      // drains vmcnt(0): tile 0 resident
  int cur = 0;
  for (int t = 0; t < nt; ++t){
    if (t+1 < nt) STAGE(cur^1);         // issue next-tile loads FIRST
    bf16x8 af[4], bfr[4];
    #pragma unroll
    for (int i=0;i<4;i++){
      af[i]  = *(const bf16x8*)(&As[cur][(wm*64 + i*16 + l15)*32 + l4*8]);
      bfr[i] = *(const bf16x8*)(&Bs[cur][(wn*64 + i*16 + l15)*32 + l4*8]);
    }
    #pragma unroll
    for (int i=0;i<4;i++)
      #pragma unroll
      for (int j=0;j<4;j++)
        acc[i][j] = MFMA16(af[i], bfr[j], acc[i][j]);
    __syncthreads();                    // drains vmcnt(0): next tile resident,
    cur ^= 1;                           // and all reads of As[cur] complete
  }

  #pragma unroll
  for (int i=0;i<4;i++){
    #pragma unroll
    for (int j=0;j<4;j++){
      #pragma unroll
      for (int r=0;r<4;r++){
        long row = m0 + wm*64 + i*16 + l4*4 + r;
        long col = n0 + wn*64 + j*16 + l15;
        float v = acc[i][j][r] + bias[col];
        if constexpr (RES)   v += res[row*(long)N + col];
        if constexpr (GELU)  v = 0.5f*v*(1.0f + erf_fast(v*0.70710678118654752f));
        if constexpr (GATEF) v *= gatef[row*(long)N + col];
        if constexpr (OBF)  ((bf16_t*)Cout)[row*(long)N + col] = f2b(v);
        else                ((float* )Cout)[row*(long)N + col] = v;
      }
    }
  }
}

// ---------------------------------------------------------------- FAVOR (MFMA)
// qkv: [16384][1536] bf16, q @ h*64, k @ 512+h*64, v @ 1024+h*64.

// dd-max over all (n,m) per bh. grid (64, 32), block 256 (4 waves x 16 rows)
__global__ __launch_bounds__(256,2)
void favor_kmax2(const bf16_t* __restrict__ qkv, const bf16_t* __restrict__ pmb,
                 unsigned* __restrict__ mxk)
{
  int bh = blockIdx.y, b = bh>>3, h = bh&7;
  int t = threadIdx.x, wid = t>>6, lane = t&63;
  int l15 = lane&15, l4 = lane>>4;
  int n0 = blockIdx.x*64, row0 = wid*16;
  f32x4 acc[18];
  #pragma unroll
  for (int c=0;c<18;c++) acc[c] = f32x4{0.f,0.f,0.f,0.f};
  const bf16_t* abase = qkv + ((size_t)(b*4096) + n0 + row0 + l15)*1536 + 512 + h*64;
  #pragma unroll
  for (int kh=0;kh<2;kh++){
    bf16x8 a = *(const bf16x8*)(abase + kh*32 + l4*8);
    #pragma unroll
    for (int ct=0;ct<18;ct++){
      bf16x8 bb = *(const bf16x8*)(pmb + (ct*16+l15)*64 + kh*32 + l4*8);
      acc[ct] = MFMA16(a, bb, acc[ct]);
    }
  }
  float mx = -3e38f;
  #pragma unroll
  for (int ct=0;ct<18;ct++){
    if (ct*16 + l15 < 266){
      #pragma unroll
      for (int r=0;r<4;r++) mx = fmaxf(mx, acc[ct][r]);
    }
  }
  #pragma unroll
  for (int o=32;o>0;o>>=1) mx = fmaxf(mx, __shfl_xor(mx, o));
  __shared__ float red[4];
  if (lane==0) red[wid] = mx;
  __syncthreads();
  if (t==0){
    float m2 = fmaxf(fmaxf(red[0],red[1]),fmaxf(red[2],red[3]));
    atomicMax(mxk + bh, encf(m2));
  }
}

// kp = ratio*(exp(dd - diag - MX)+eps) -> kp[bhl][n][MPAD]. grid (64, KG)
__global__ __launch_bounds__(256,2)
void favor_kp(const bf16_t* __restrict__ qkv, const bf16_t* __restrict__ pmb,
              const unsigned* __restrict__ mxk, const float* __restrict__ diagk,
              bf16_t* __restrict__ kp, int bh0)
{
  int bhl = blockIdx.y, bh = bh0 + bhl, b = bh>>3, h = bh&7;
  int t = threadIdx.x, wid = t>>6, lane = t&63;
  int l15 = lane&15, l4 = lane>>4;
  int n0 = blockIdx.x*64, row0 = wid*16;
  f32x4 acc[18];
  #pragma unroll
  for (int c=0;c<18;c++) acc[c] = f32x4{0.f,0.f,0.f,0.f};
  const bf16_t* abase = qkv + ((size_t)(b*4096) + n0 + row0 + l15)*1536 + 512 + h*64;
  #pragma unroll
  for (int kh=0;kh<2;kh++){
    bf16x8 a = *(const bf16x8*)(abase + kh*32 + l4*8);
    #pragma unroll
    for (int ct=0;ct<18;ct++){
      bf16x8 bb = *(const bf16x8*)(pmb + (ct*16+l15)*64 + kh*32 + l4*8);
      acc[ct] = MFMA16(a, bb, acc[ct]);
    }
  }
  float MX = decf(mxk[bh]);
  float dg[4];
  #pragma unroll
  for (int r=0;r<4;r++) dg[r] = diagk[(size_t)bh*4096 + n0 + row0 + l4*4 + r];
  #pragma unroll
  for (int ct=0;ct<18;ct++){
    int col = ct*16 + l15;
    #pragma unroll
    for (int r=0;r<4;r++){
      float v = (col < 266) ? RATIO*(__expf(acc[ct][r] - dg[r] - MX) + KEPS) : 0.f;
      kp[((size_t)bhl*4096 + n0 + row0 + l4*4 + r)*MPAD + col] = f2b(v);
    }
  }
}

// kp [bhl][4096][MPAD] -> kpT [bhl][MPAD][4096]. grid (128, 9, KG)
__global__ __launch_bounds__(256)
void trans_kp(const bf16_t* __restrict__ kp, bf16_t* __restrict__ kpT)
{
  __shared__ ushort ts[32][36];
  int bhl = blockIdx.z;
  int n0 = blockIdx.x*32, m0 = blockIdx.y*32;
  int t = threadIdx.x, r = t>>3, c4 = (t&7)*4;
  ushort4 v = *(const ushort4*)(kp + ((size_t)bhl*4096 + n0 + r)*MPAD + m0 + c4);
  ts[r][c4+0]=v.x; ts[r][c4+1]=v.y; ts[r][c4+2]=v.z; ts[r][c4+3]=v.w;
  __syncthreads();
  ushort4 o;
  o.x = ts[c4+0][r]; o.y = ts[c4+1][r]; o.z = ts[c4+2][r]; o.w = ts[c4+3][r];
  *(ushort4*)(kpT + ((size_t)bhl*MPAD + m0 + r)*4096 + n0 + c4) = o;
}

// ksum[m] = sum_n kp. one wave per m-row. grid (KG*68)
__global__ __launch_bounds__(256)
void ksum_kernel(const bf16_t* __restrict__ kpT, float* __restrict__ ksumf, int bh0)
{
  int t = threadIdx.x, wid = t>>6, lane = t&63;
  int rr = blockIdx.x*4 + wid;
  int bhl = rr/272, m = rr%272;
  const bf16_t* row = kpT + ((size_t)bhl*MPAD + m)*4096;
  float s = 0.f;
  #pragma unroll
  for (int j=0;j<8;j++){
    bf16x8 v = *(const bf16x8*)(row + j*512 + lane*8);
    #pragma unroll
    for (int e=0;e<8;e++) s += b2f((bf16_t)v[e]);
  }
  #pragma unroll
  for (int o=32;o>0;o>>=1) s += __shfl_xor(s, o);
  if (lane==0) ksumf[(size_t)(bh0+bhl)*MPAD + m] = s;
}

// ctx GEMM: ctxT[bh][d][m] = sum_n kpT[m][n]*vT[d][n]. grid (17, KG)
__global__ __launch_bounds__(256,2)
void ctx_gemm(const bf16_t* __restrict__ kpT, const bf16_t* __restrict__ vT,
              bf16_t* __restrict__ ctxT, int bh0)
{
  int bhl = blockIdx.y, bh = bh0 + bhl;
  int t = threadIdx.x, wid = t>>6, lane = t&63;
  int l15 = lane&15, l4 = lane>>4;
  int m0 = blockIdx.x*16;
  f32x4 acc[4];
  #pragma unroll
  for (int c=0;c<4;c++) acc[c] = f32x4{0.f,0.f,0.f,0.f};
  const bf16_t* Abase = kpT + ((size_t)bhl*MPAD + m0 + l15)*4096;
  const bf16_t* Bbase = vT + ((size_t)bh*64)*4096;
  for (int k = wid*1024; k < wid*1024 + 1024; k += 32){
    bf16x8 a = *(const bf16x8*)(Abase + k + l4*8);
    #pragma unroll
    for (int ct=0;ct<4;ct++){
      bf16x8 bb = *(const bf16x8*)(Bbase + (size_t)(ct*16+l15)*4096 + k + l4*8);
      acc[ct] = MFMA16(a, bb, acc[ct]);
    }
  }
  __shared__ float red[4][4][16][16];
  #pragma unroll
  for (int ct=0;ct<4;ct++)
    #pragma unroll
    for (int r=0;r<4;r++) red[wid][ct][l4*4+r][l15] = acc[ct][r];
  __syncthreads();
  #pragma unroll
  for (int i=0;i<4;i++){
    int e = i*256 + t;
    int ct = e>>8, row = (e>>4)&15, col = e&15;
    float s = ((red[0][ct][row][col] + red[1][ct][row][col])
             + (red[2][ct][row][col] + red[3][ct][row][col]));
    ctxT[((size_t)bh*64 + ct*16 + col)*MPAD + m0 + row] = f2b(s);
  }
}

// fused q-side: dd MFMA -> rowmax -> qp -> LDS -> out MFMA * dinv -> attn
// grid (64, 32), block 256 (4 waves x 16 rows)
__global__ __launch_bounds__(256,2)
void favor_q(const bf16_t* __restrict__ qkv, const bf16_t* __restrict__ pmb,
             const float* __restrict__ diagq, const float* __restrict__ ksumf,
             const bf16_t* __restrict__ ctxT, bf16_t* __restrict__ attn)
{
  __shared__ alignas(16) ushort qpLds[64*296];
  __shared__ float ksLds[288];
  int bh = blockIdx.y, b = bh>>3, h = bh&7;
  int t = threadIdx.x, wid = t>>6, lane = t&63;
  int l15 = lane&15, l4 = lane>>4;
  int n0 = blockIdx.x*64, row0 = wid*16;
  ksLds[t] = ksumf[(size_t)bh*MPAD + t];
  if (t < 32) ksLds[256+t] = ksumf[(size_t)bh*MPAD + 256 + t];
  __syncthreads();

  f32x4 acc[18];
  #pragma unroll
  for (int c=0;c<18;c++) acc[c] = f32x4{0.f,0.f,0.f,0.f};
  const bf16_t* abase = qkv + ((size_t)(b*4096) + n0 + row0 + l15)*1536 + h*64;
  #pragma unroll
  for (int kh=0;kh<2;kh++){
    bf16x8 a = *(const bf16x8*)(abase + kh*32 + l4*8);
    #pragma unroll
    for (int ct=0;ct<18;ct++){
      bf16x8 bb = *(const bf16x8*)(pmb + (ct*16+l15)*64 + kh*32 + l4*8);
      acc[ct] = MFMA16(a, bb, acc[ct]);
    }
  }
  // per-row max over valid cols
  float mxr[4] = {-3e38f,-3e38f,-3e38f,-3e38f};
  #pragma unroll
  for (int ct=0;ct<18;ct++){
    if (ct*16 + l15 < 266){
      #pragma unroll
      for (int r=0;r<4;r++) mxr[r] = fmaxf(mxr[r], acc[ct][r]);
    }
  }
  #pragma unroll
  for (int r=0;r<4;r++){
    mxr[r] = fmaxf(mxr[r], __shfl_xor(mxr[r], 1));
    mxr[r] = fmaxf(mxr[r], __shfl_xor(mxr[r], 2));
    mxr[r] = fmaxf(mxr[r], __shfl_xor(mxr[r], 4));
    mxr[r] = fmaxf(mxr[r], __shfl_xor(mxr[r], 8));
  }
  float dg[4];
  #pragma unroll
  for (int r=0;r<4;r++) dg[r] = diagq[(size_t)bh*4096 + n0 + row0 + l4*4 + r];
  float den[4] = {0.f,0.f,0.f,0.f};
  #pragma unroll
  for (int ct=0;ct<18;ct++){
    int col = ct*16 + l15;
    float ks = ksLds[col];
    #pragma unroll
    for (int r=0;r<4;r++){
      float qpv = 0.f;
      if (col < 266){
        qpv = RATIO*(__expf(acc[ct][r] - dg[r] - mxr[r]) + KEPS);
        den[r] += qpv*ks;
      }
      qpLds[(row0 + l4*4 + r)*296 + col] = f2b(qpv);
    }
  }
  float dinv[4];
  #pragma unroll
  for (int r=0;r<4;r++){
    den[r] += __shfl_xor(den[r], 1);
    den[r] += __shfl_xor(den[r], 2);
    den[r] += __shfl_xor(den[r], 4);
    den[r] += __shfl_xor(den[r], 8);
    dinv[r] = 1.0f/den[r];
  }
  __syncthreads();

  f32x4 o2[4];
  #pragma unroll
  for (int c=0;c<4;c++) o2[c] = f32x4{0.f,0.f,0.f,0.f};
  const bf16_t* Bbase = ctxT + (size_t)bh*64*MPAD;
  #pragma unroll
  for (int kk=0;kk<9;kk++){
    int k0 = kk*32;
    bf16x8 a = *(const bf16x8*)&qpLds[(row0 + l15)*296 + k0 + l4*8];
    #pragma unroll
    for (int ct=0;ct<4;ct++){
      bf16x8 bb = *(const bf16x8*)(Bbase + (size_t)(ct*16+l15)*MPAD + k0 + l4*8);
      o2[ct] = MFMA16(a, bb, o2[ct]);
    }
  }
  #pragma unroll
  for (int ct=0;ct<4;ct++)
    #pragma unroll
    for (int r=0;r<4;r++)
      attn[((size_t)(b*4096) + n0 + row0 + l4*4 + r)*512 + h*64 + ct*16 + l15]
        = f2b(o2[ct][r] * dinv[r]);
}

// ---------------------------------------------------------------- launcher
extern "C" void kernel_launch(void* const* d_in, const int* in_sizes, int n_in,
                              void* d_out, int out_size, void* d_ws, size_t ws_size,
                              hipStream_t stream)
{
  (void)in_sizes; (void)n_in; (void)out_size;
  const float* x      = (const float*)d_in[0];
  const float* proj_w = (const float*)d_in[1];
  const float* proj_b = (const float*)d_in[2];
  const float* ln1_g  = (const float*)d_in[3];
  const float* ln1_b  = (const float*)d_in[4];
  const float* wq     = (const float*)d_in[5];
  const float* bq     = (const float*)d_in[6];
  const float* wk     = (const float*)d_in[7];
  const float* bk     = (const float*)d_in[8];
  const float* wv     = (const float*)d_in[9];
  const float* bv     = (const float*)d_in[10];
  const float* wo     = (const float*)d_in[11];
  const float* bo     = (const float*)d_in[12];
  const float* pm     = (const float*)d_in[13];
  const float* ln2_g  = (const float*)d_in[14];
  const float* ln2_b  = (const float*)d_in[15];
  const float* w1     = (const float*)d_in[16];
  const float* b1     = (const float*)d_in[17];
  const float* w2     = (const float*)d_in[18];
  const float* b2     = (const float*)d_in[19];
  float* out = (float*)d_out;
  const size_t MB = 1ull<<20;

  char* ws = (char*)d_ws;
  size_t off = 0;
  auto alloc = [&](size_t bytes)->void*{ void* p = ws + off; off += (bytes + 255) & ~(size_t)255; return p; };
  bf16_t* Wt_proj = (bf16_t*)alloc(2ul*1024*1024);
  bf16_t* Wt_qkv  = (bf16_t*)alloc(2ul*1536*1024);
  bf16_t* Wt_o    = (bf16_t*)alloc(2ul*1024*512);
  bf16_t* Wt_1    = (bf16_t*)alloc(2ul*4096*1024);
  bf16_t* Wt_2    = (bf16_t*)alloc(2ul*1024*4096);
  float*  bqkv    = (float*) alloc(4ul*1536);
  unsigned* mxk   = (unsigned*)alloc(4ul*32);
  bf16_t* pmb     = (bf16_t*)alloc(2ul*MPAD*64);
  float*  diagq   = (float*) alloc(4ul*32*4096);
  float*  diagk   = (float*) alloc(4ul*32*4096);
  float*  ksumf   = (float*) alloc(4ul*32*MPAD);
  bf16_t* ctxT    = (bf16_t*)alloc(2ul*32*64*MPAD);
  char*   R       = (char*)  alloc(0);
  size_t R_avail = (ws_size > off) ? ws_size - off : 0;

  // region floor: phase A 64MB, k-side KG=4 67MB, ff NC=4 50MB
  if (R_avail < 67*MB){ zero_out<<<dim3(65536), 256, 0, stream>>>(out, 16777216L); return; }
  int KG = (R_avail >= 87*MB) ? 8 : 4;    // k-side top: 48 + 2*KG*2.36MB
  int NC = (R_avail >= 84*MB) ? 2 : 4;    // ff top: 16 + (16384/NC)*8KB

  // R overlays (stream-serialized disjoint lifetimes)
  bf16_t* qkv  = (bf16_t*)(R);               // 48MB   [LN1/qkv .. favor_q]
  bf16_t* h1c  = (bf16_t*)(R + 48*MB);       // 16MB   [phase A]
  bf16_t* kp   = (bf16_t*)(R + 48*MB);       // KG*2.36MB [k-side]
  bf16_t* kpT  = (bf16_t*)(R + 48*MB + (size_t)KG*4096*MPAD*2 + 1*MB);
  bf16_t* attn = (bf16_t*)(R + 48*MB);       // 16MB   [favor_q .. wo]
  long    CH   = 16384/NC;
  bf16_t* h2c  = (bf16_t*)(R);               // reused as xbc too
  bf16_t* ff1c = (bf16_t*)(R + 16*MB);       // CH*8KB
  bf16_t* vT   = (bf16_t*)d_out;             // 16.8MB scratch in d_out (dead till wo)

  // 1) weights -> bf16 transposed, pm cast
  wt_cast<<<dim3(32,32), 256, 0, stream>>>(proj_w, Wt_proj, 1024, 1024);
  wt_cast<<<dim3(32,16), 256, 0, stream>>>(wq, Wt_qkv,              1024, 512);
  wt_cast<<<dim3(32,16), 256, 0, stream>>>(wk, Wt_qkv + 512*1024,   1024, 512);
  wt_cast<<<dim3(32,16), 256, 0, stream>>>(wv, Wt_qkv + 1024*1024,  1024, 512);
  wt_cast<<<dim3(16,32), 256, 0, stream>>>(wo, Wt_o, 512, 1024);
  wt_cast<<<dim3(32,128),256, 0, stream>>>(w1, Wt_1, 1024, 4096);
  wt_cast<<<dim3(128,32),256, 0, stream>>>(w2, Wt_2, 4096, 1024);
  concat_bias<<<dim3(6), 256, 0, stream>>>(bq, bk, bv, bqkv);
  pm_cast<<<dim3(72), 256, 0, stream>>>(pm, pmb);

  // 2) phase A: LN1 + qkv GEMM, 2 chunks of 8192 rows
  for (int c = 0; c < 2; c++){
    ln_kernel<<<dim3(8192), 256, 0, stream>>>(x + (size_t)c*8192*1024, ln1_g, ln1_b, h1c);
    gemm_bt<0,0,0,1><<<dim3(12,64), 256, 0, stream>>>(h1c, 1024, Wt_qkv, 1024,
        bqkv, nullptr, nullptr, qkv + (size_t)c*8192*1536, 1536, 1024);
  }

  // 3) FAVOR
  diag_kernel<<<dim3(16,32), 256, 0, stream>>>(qkv, diagq, diagk);
  vt_trans<<<dim3(128,64), 256, 0, stream>>>(qkv, vT);
  mx_init<<<dim3(1), 64, 0, stream>>>(mxk);
  favor_kmax2<<<dim3(64,32), 256, 0, stream>>>(qkv, pmb, mxk);
  for (int g = 0; g < 32; g += KG){
    favor_kp<<<dim3(64,KG), 256, 0, stream>>>(qkv, pmb, mxk, diagk, kp, g);
    trans_kp<<<dim3(128,9,KG), 256, 0, stream>>>(kp, kpT);
    ksum_kernel<<<dim3(KG*68), 256, 0, stream>>>(kpT, ksumf, g);
    ctx_gemm<<<dim3(17,KG), 256, 0, stream>>>(kpT, vT, ctxT, g);
  }
  favor_q<<<dim3(64,32), 256, 0, stream>>>(qkv, pmb, diagq, ksumf, ctxT, attn);

  // 4) x2 = x + attn @ wo + bo -> d_out (f32); overwrites vT scratch
  gemm_bt<1,0,0,0><<<dim3(8,128), 256, 0, stream>>>(attn, 512, Wt_o, 512,
      bo, x, nullptr, out, 1024, 512);

  // 5) per chunk: LN2 -> ff1(gelu) -> ff2(+res, in-place) -> gate(in-place)
  for (int c = 0; c < NC; c++){
    float* xrow = out + (size_t)c*CH*1024;
    ln_kernel<<<dim3((unsigned)CH), 256, 0, stream>>>(xrow, ln2_g, ln2_b, h2c);
    gemm_bt<0,1,0,1><<<dim3(32,(unsigned)(CH/128)), 256, 0, stream>>>(h2c, 1024, Wt_1, 1024,
        b1, nullptr, nullptr, ff1c, 4096, 1024);
    gemm_bt<1,0,0,0><<<dim3(8,(unsigned)(CH/128)), 256, 0, stream>>>(ff1c, 4096, Wt_2, 4096,
        b2, xrow, nullptr, xrow, 1024, 4096);
    cast_f32_bf16<<<dim3((unsigned)CH), 256, 0, stream>>>(x + (size_t)c*CH*1024, h2c);
    gemm_bt<0,0,1,0><<<dim3(8,(unsigned)(CH/128)), 256, 0, stream>>>(h2c, 1024, Wt_proj, 1024,
        proj_b, nullptr, xrow, xrow, 1024, 1024);
  }
}